// Round 1
// baseline (1474.765 us; speedup 1.0000x reference)
//
#include <hip/hip_runtime.h>

#define NN 30000
#define NE 480000
#define CH 64
#define NH 4
#define BN_EPS 1e-5f

// ---------------------------------------------------------------------------
// Detect whether edge_index is stored as int64 (all odd 32-bit words zero)
// or int32. Writes flag (1 = int64) into ws.
// ---------------------------------------------------------------------------
__global__ __launch_bounds__(64) void detect_kernel(const unsigned int* __restrict__ ei,
                                                    int* __restrict__ flag) {
    if (threadIdx.x == 0 && blockIdx.x == 0) {
        int all0 = 1;
        for (int i = 0; i < 64; ++i) {
            if (ei[2 * i + 1] != 0u) all0 = 0;
        }
        *flag = all0;
    }
}

__device__ __forceinline__ int load_idx(const void* ei, int is64, int pos) {
    if (is64) return (int)((const long long*)ei)[pos];
    return ((const int*)ei)[pos];
}

// ---------------------------------------------------------------------------
// Degree of each dst node (real edges only; self loop added in finalize).
// ---------------------------------------------------------------------------
__global__ __launch_bounds__(256) void deg_kernel(const void* __restrict__ ei,
                                                  const int* __restrict__ flag,
                                                  float* __restrict__ deg) {
    int e = blockIdx.x * 256 + threadIdx.x;
    if (e >= NE) return;
    int is64 = *flag;
    int d = load_idx(ei, is64, NE + e);
    atomicAdd(&deg[d], 1.0f);
}

// ---------------------------------------------------------------------------
// Node transform: y[n, 0..255] = h[n,:] @ W^T ; p[n, 0..3] = h[n,:] @ U^T
// One thread per node; h row held in registers; W/U via uniform (scalar) loads.
// ---------------------------------------------------------------------------
__global__ __launch_bounds__(256) void transform_kernel(const float* __restrict__ h,
                                                        const float* __restrict__ W,
                                                        const float* __restrict__ U,
                                                        float* __restrict__ y,
                                                        float* __restrict__ p) {
    int n = blockIdx.x * 256 + threadIdx.x;
    if (n >= NN) return;
    float hr[64];
    const float4* h4 = reinterpret_cast<const float4*>(h + (size_t)n * 64);
#pragma unroll
    for (int j = 0; j < 16; ++j) {
        float4 v = h4[j];
        hr[4 * j + 0] = v.x; hr[4 * j + 1] = v.y;
        hr[4 * j + 2] = v.z; hr[4 * j + 3] = v.w;
    }
    float* yb = y + (size_t)n * 256;
    for (int o = 0; o < 256; o += 4) {
        float4 acc = make_float4(0.f, 0.f, 0.f, 0.f);
#pragma unroll
        for (int k = 0; k < 64; ++k) {
            acc.x += hr[k] * W[(o + 0) * 64 + k];
            acc.y += hr[k] * W[(o + 1) * 64 + k];
            acc.z += hr[k] * W[(o + 2) * 64 + k];
            acc.w += hr[k] * W[(o + 3) * 64 + k];
        }
        *reinterpret_cast<float4*>(yb + o) = acc;
    }
    float4 pv = make_float4(0.f, 0.f, 0.f, 0.f);
#pragma unroll
    for (int k = 0; k < 64; ++k) {
        pv.x += hr[k] * U[0 * 64 + k];
        pv.y += hr[k] * U[1 * 64 + k];
        pv.z += hr[k] * U[2 * 64 + k];
        pv.w += hr[k] * U[3 * 64 + k];
    }
    *reinterpret_cast<float4*>(p + (size_t)n * 4) = pv;
}

// ---------------------------------------------------------------------------
// Edge kernel: one wave per edge, lane = output channel.
// attn = softmax(p[dst]-p[src]+c); msg = sum_m attn_m * y[src, m*64+lane];
// atomicAdd into agg[dst*64+lane].
// ---------------------------------------------------------------------------
__global__ __launch_bounds__(256) void edge_kernel(const void* __restrict__ ei,
                                                   const int* __restrict__ flag,
                                                   const float* __restrict__ p,
                                                   const float* __restrict__ y,
                                                   const float* __restrict__ cvec,
                                                   float* __restrict__ agg) {
    int e = blockIdx.x * 4 + (threadIdx.x >> 6);
    int lane = threadIdx.x & 63;
    if (e >= NE) return;
    int is64 = *flag;
    int s = load_idx(ei, is64, e);
    int d = load_idx(ei, is64, NE + e);

    float4 ps = *reinterpret_cast<const float4*>(p + (size_t)s * 4);
    float4 pd = *reinterpret_cast<const float4*>(p + (size_t)d * 4);
    float l0 = pd.x - ps.x + cvec[0];
    float l1 = pd.y - ps.y + cvec[1];
    float l2 = pd.z - ps.z + cvec[2];
    float l3 = pd.w - ps.w + cvec[3];
    float mx = fmaxf(fmaxf(l0, l1), fmaxf(l2, l3));
    float a0 = __expf(l0 - mx);
    float a1 = __expf(l1 - mx);
    float a2 = __expf(l2 - mx);
    float a3 = __expf(l3 - mx);
    float inv = 1.0f / (a0 + a1 + a2 + a3);

    const float* yb = y + (size_t)s * 256;
    float msg = (a0 * yb[lane] + a1 * yb[64 + lane] +
                 a2 * yb[128 + lane] + a3 * yb[192 + lane]) * inv;
    atomicAdd(&agg[(size_t)d * 64 + lane], msg);
}

// ---------------------------------------------------------------------------
// Finalize: add self-loop message (attn = softmax(c), same for every node),
// divide by (deg+1), add bias. Optionally ReLU + accumulate BN stats.
// Grid is exact: NN*CH / 256 blocks.
// ---------------------------------------------------------------------------
template <int DO_RELU_STATS>
__global__ __launch_bounds__(256) void finalize_kernel(const float* __restrict__ agg,
                                                       const float* __restrict__ deg,
                                                       const float* __restrict__ y,
                                                       const float* __restrict__ cvec,
                                                       const float* __restrict__ bvec,
                                                       float* __restrict__ hout,
                                                       float* __restrict__ stats) {
    int tid = blockIdx.x * 256 + threadIdx.x;
    int n = tid >> 6;
    int o = tid & 63;

    float l0 = cvec[0], l1 = cvec[1], l2 = cvec[2], l3 = cvec[3];
    float mx = fmaxf(fmaxf(l0, l1), fmaxf(l2, l3));
    float a0 = __expf(l0 - mx);
    float a1 = __expf(l1 - mx);
    float a2 = __expf(l2 - mx);
    float a3 = __expf(l3 - mx);
    float inv = 1.0f / (a0 + a1 + a2 + a3);

    const float* yb = y + (size_t)n * 256;
    float self = (a0 * yb[o] + a1 * yb[64 + o] + a2 * yb[128 + o] + a3 * yb[192 + o]) * inv;
    float val = (agg[tid] + self) / (deg[n] + 1.0f) + bvec[o];

    if (DO_RELU_STATS) {
        val = fmaxf(val, 0.0f);
        hout[tid] = val;
        __shared__ float s1[256];
        __shared__ float s2[256];
        s1[threadIdx.x] = val;
        s2[threadIdx.x] = val * val;
        __syncthreads();
        if (threadIdx.x < 64) {
            float s = s1[threadIdx.x] + s1[threadIdx.x + 64] +
                      s1[threadIdx.x + 128] + s1[threadIdx.x + 192];
            float q = s2[threadIdx.x] + s2[threadIdx.x + 64] +
                      s2[threadIdx.x + 128] + s2[threadIdx.x + 192];
            atomicAdd(&stats[threadIdx.x], s);
            atomicAdd(&stats[64 + threadIdx.x], q);
        }
    } else {
        hout[tid] = val;
    }
}

// ---------------------------------------------------------------------------
// BatchNorm apply (training-mode biased stats), in place.
// ---------------------------------------------------------------------------
__global__ __launch_bounds__(256) void bn_kernel(float* __restrict__ h,
                                                 const float* __restrict__ stats,
                                                 const float* __restrict__ g,
                                                 const float* __restrict__ bt) {
    int tid = blockIdx.x * 256 + threadIdx.x;
    int o = tid & 63;
    const float invN = 1.0f / (float)NN;
    float mu = stats[o] * invN;
    float var = stats[64 + o] * invN - mu * mu;
    float sc = rsqrtf(var + BN_EPS) * g[o];
    h[tid] = (h[tid] - mu) * sc + bt[o];
}

extern "C" void kernel_launch(void* const* d_in, const int* in_sizes, int n_in,
                              void* d_out, int out_size, void* d_ws, size_t ws_size,
                              hipStream_t stream) {
    const float* x = (const float*)d_in[0];
    const void* ei = d_in[1];
    const float* W0 = (const float*)d_in[2];
    const float* U0 = (const float*)d_in[3];
    const float* c0 = (const float*)d_in[4];
    const float* b0 = (const float*)d_in[5];
    const float* g0 = (const float*)d_in[6];
    const float* bt0 = (const float*)d_in[7];
    const float* W1 = (const float*)d_in[8];
    const float* U1 = (const float*)d_in[9];
    const float* c1 = (const float*)d_in[10];
    const float* b1 = (const float*)d_in[11];
    const float* g1 = (const float*)d_in[12];
    const float* bt1 = (const float*)d_in[13];
    const float* W2 = (const float*)d_in[14];
    const float* U2 = (const float*)d_in[15];
    const float* c2 = (const float*)d_in[16];
    const float* b2 = (const float*)d_in[17];

    float* ws = (float*)d_ws;
    float* y = ws;                        // NN*256
    float* p = y + (size_t)NN * 256;      // NN*4
    float* agg = p + (size_t)NN * 4;      // NN*64
    float* h1 = agg + (size_t)NN * 64;    // NN*64
    float* h2 = h1 + (size_t)NN * 64;     // NN*64
    float* stats = h2 + (size_t)NN * 64;  // 128
    float* deg = stats + 128;             // NN
    int* flag = (int*)(deg + NN);         // 1

    const int TB = 256;
    const int nodeBlocks = (NN + TB - 1) / TB;       // 118
    const int edgeBlocks = NE / 4;                   // 120000 (one wave per edge)
    const int ncBlocks = (NN * CH) / TB;             // 7500 exact
    const int degBlocks = NE / TB;                   // 1875 exact

    detect_kernel<<<1, 64, 0, stream>>>((const unsigned int*)ei, flag);
    hipMemsetAsync(deg, 0, sizeof(float) * NN, stream);
    deg_kernel<<<degBlocks, TB, 0, stream>>>(ei, flag, deg);

    // ---- layer 0 ----
    transform_kernel<<<nodeBlocks, TB, 0, stream>>>(x, W0, U0, y, p);
    hipMemsetAsync(agg, 0, sizeof(float) * (size_t)NN * 64, stream);
    edge_kernel<<<edgeBlocks, TB, 0, stream>>>(ei, flag, p, y, c0, agg);
    hipMemsetAsync(stats, 0, sizeof(float) * 128, stream);
    finalize_kernel<1><<<ncBlocks, TB, 0, stream>>>(agg, deg, y, c0, b0, h1, stats);
    bn_kernel<<<ncBlocks, TB, 0, stream>>>(h1, stats, g0, bt0);

    // ---- layer 1 ----
    transform_kernel<<<nodeBlocks, TB, 0, stream>>>(h1, W1, U1, y, p);
    hipMemsetAsync(agg, 0, sizeof(float) * (size_t)NN * 64, stream);
    edge_kernel<<<edgeBlocks, TB, 0, stream>>>(ei, flag, p, y, c1, agg);
    hipMemsetAsync(stats, 0, sizeof(float) * 128, stream);
    finalize_kernel<1><<<ncBlocks, TB, 0, stream>>>(agg, deg, y, c1, b1, h2, stats);
    bn_kernel<<<ncBlocks, TB, 0, stream>>>(h2, stats, g1, bt1);

    // ---- layer 2 ----
    transform_kernel<<<nodeBlocks, TB, 0, stream>>>(h2, W2, U2, y, p);
    hipMemsetAsync(agg, 0, sizeof(float) * (size_t)NN * 64, stream);
    edge_kernel<<<edgeBlocks, TB, 0, stream>>>(ei, flag, p, y, c2, agg);
    finalize_kernel<0><<<ncBlocks, TB, 0, stream>>>(agg, deg, y, c2, b2, (float*)d_out, nullptr);
}

// Round 2
// 1022.437 us; speedup vs baseline: 1.4424x; 1.4424x over previous
//
#include <hip/hip_runtime.h>

#define NN 30000
#define NE 480000
#define CH 64
#define NH 4
#define BN_EPS 1e-5f

// ---------------------------------------------------------------------------
// Detect whether edge_index is stored as int64 (all odd 32-bit words zero)
// or int32. Writes flag (1 = int64) into ws.
// ---------------------------------------------------------------------------
__global__ __launch_bounds__(64) void detect_kernel(const unsigned int* __restrict__ ei,
                                                    int* __restrict__ flag) {
    if (threadIdx.x == 0 && blockIdx.x == 0) {
        int all0 = 1;
        for (int i = 0; i < 64; ++i) {
            if (ei[2 * i + 1] != 0u) all0 = 0;
        }
        *flag = all0;
    }
}

__device__ __forceinline__ int load_idx(const void* ei, int is64, int pos) {
    if (is64) return (int)((const long long*)ei)[pos];
    return ((const int*)ei)[pos];
}

// ---------------------------------------------------------------------------
// Degree of each dst node (real edges only; self loop added in finalize).
// ---------------------------------------------------------------------------
__global__ __launch_bounds__(256) void deg_kernel(const void* __restrict__ ei,
                                                  const int* __restrict__ flag,
                                                  float* __restrict__ deg) {
    int e = blockIdx.x * 256 + threadIdx.x;
    if (e >= NE) return;
    int is64 = *flag;
    int d = load_idx(ei, is64, NE + e);
    atomicAdd(&deg[d], 1.0f);
}

// ---------------------------------------------------------------------------
// One-shot transpose of the three W matrices into wt4 layout:
//   wt4[layer][(k*64 + l)*4 + m] = W_layer[(m*64 + l)*64 + k]
// so the transform kernel reads one coalesced float4 per (k, lane).
// ---------------------------------------------------------------------------
__global__ __launch_bounds__(256) void transpose_kernel(const float* __restrict__ W0,
                                                        const float* __restrict__ W1,
                                                        const float* __restrict__ W2,
                                                        float* __restrict__ wt) {
    int t = blockIdx.x * 256 + threadIdx.x;      // 3 * 16384 threads
    if (t >= 3 * 16384) return;
    int layer = t / 16384;
    int r = t & 16383;
    int m = r & 3;
    int l = (r >> 2) & 63;
    int k = r >> 8;
    const float* W = (layer == 0) ? W0 : (layer == 1) ? W1 : W2;
    wt[t] = W[(m * 64 + l) * 64 + k];
}

// ---------------------------------------------------------------------------
// Node transform: y[n, 0..255] = h[n,:] @ W^T
// One wave per 4 nodes; lane = base output channel (computes o = m*64+lane).
// W comes from the pre-transposed wt4 (coalesced float4 per k).
// h rows are wave-uniform float4 broadcasts.
// ---------------------------------------------------------------------------
__global__ __launch_bounds__(256) void transform_kernel(const float* __restrict__ h,
                                                        const float4* __restrict__ wt4,
                                                        float* __restrict__ y) {
    int wave = (blockIdx.x * 256 + threadIdx.x) >> 6;  // 0..7499 (exact)
    int lane = threadIdx.x & 63;
    int n0 = wave * 4;
    const float4* h4 = reinterpret_cast<const float4*>(h);

    float acc[4][4];
#pragma unroll
    for (int j = 0; j < 4; ++j)
#pragma unroll
        for (int m = 0; m < 4; ++m) acc[j][m] = 0.0f;

#pragma unroll 4
    for (int kb = 0; kb < 16; ++kb) {
        float hb[4][4];
#pragma unroll
        for (int j = 0; j < 4; ++j) {
            float4 v = h4[(size_t)(n0 + j) * 16 + kb];
            hb[j][0] = v.x; hb[j][1] = v.y; hb[j][2] = v.z; hb[j][3] = v.w;
        }
#pragma unroll
        for (int kk = 0; kk < 4; ++kk) {
            float4 wv = wt4[(size_t)(kb * 4 + kk) * 64 + lane];
#pragma unroll
            for (int j = 0; j < 4; ++j) {
                acc[j][0] += hb[j][kk] * wv.x;
                acc[j][1] += hb[j][kk] * wv.y;
                acc[j][2] += hb[j][kk] * wv.z;
                acc[j][3] += hb[j][kk] * wv.w;
            }
        }
    }
#pragma unroll
    for (int j = 0; j < 4; ++j)
#pragma unroll
        for (int m = 0; m < 4; ++m)
            y[(size_t)(n0 + j) * 256 + m * 64 + lane] = acc[j][m];
}

// ---------------------------------------------------------------------------
// p[n, m] = h[n,:] @ U[m,:]   — thread per (node, head)
// ---------------------------------------------------------------------------
__global__ __launch_bounds__(256) void p_kernel(const float* __restrict__ h,
                                                const float* __restrict__ U,
                                                float* __restrict__ p) {
    int t = blockIdx.x * 256 + threadIdx.x;
    if (t >= NN * NH) return;
    int n = t >> 2;
    int m = t & 3;
    const float4* h4 = reinterpret_cast<const float4*>(h) + (size_t)n * 16;
    const float4* U4 = reinterpret_cast<const float4*>(U) + (size_t)m * 16;
    float acc = 0.0f;
#pragma unroll
    for (int j = 0; j < 16; ++j) {
        float4 hv = h4[j];
        float4 uv = U4[j];
        acc += hv.x * uv.x + hv.y * uv.y + hv.z * uv.z + hv.w * uv.w;
    }
    p[t] = acc;
}

// ---------------------------------------------------------------------------
// Edge kernel: one wave per edge, lane = output channel.
// attn = softmax(p[dst]-p[src]+c); msg = sum_m attn_m * y[src, m*64+lane];
// atomicAdd into agg[dst*64+lane].
// ---------------------------------------------------------------------------
__global__ __launch_bounds__(256) void edge_kernel(const void* __restrict__ ei,
                                                   const int* __restrict__ flag,
                                                   const float* __restrict__ p,
                                                   const float* __restrict__ y,
                                                   const float* __restrict__ cvec,
                                                   float* __restrict__ agg) {
    int e = blockIdx.x * 4 + (threadIdx.x >> 6);
    int lane = threadIdx.x & 63;
    if (e >= NE) return;
    int is64 = *flag;
    int s = load_idx(ei, is64, e);
    int d = load_idx(ei, is64, NE + e);

    float4 ps = *reinterpret_cast<const float4*>(p + (size_t)s * 4);
    float4 pd = *reinterpret_cast<const float4*>(p + (size_t)d * 4);
    float l0 = pd.x - ps.x + cvec[0];
    float l1 = pd.y - ps.y + cvec[1];
    float l2 = pd.z - ps.z + cvec[2];
    float l3 = pd.w - ps.w + cvec[3];
    float mx = fmaxf(fmaxf(l0, l1), fmaxf(l2, l3));
    float a0 = __expf(l0 - mx);
    float a1 = __expf(l1 - mx);
    float a2 = __expf(l2 - mx);
    float a3 = __expf(l3 - mx);
    float inv = 1.0f / (a0 + a1 + a2 + a3);

    const float* yb = y + (size_t)s * 256;
    float msg = (a0 * yb[lane] + a1 * yb[64 + lane] +
                 a2 * yb[128 + lane] + a3 * yb[192 + lane]) * inv;
    atomicAdd(&agg[(size_t)d * 64 + lane], msg);
}

// ---------------------------------------------------------------------------
// Finalize: add self-loop message (attn = softmax(c), same for every node),
// divide by (deg+1), add bias. Optionally ReLU + accumulate BN stats.
// ---------------------------------------------------------------------------
template <int DO_RELU_STATS>
__global__ __launch_bounds__(256) void finalize_kernel(const float* __restrict__ agg,
                                                       const float* __restrict__ deg,
                                                       const float* __restrict__ y,
                                                       const float* __restrict__ cvec,
                                                       const float* __restrict__ bvec,
                                                       float* __restrict__ hout,
                                                       float* __restrict__ stats) {
    int tid = blockIdx.x * 256 + threadIdx.x;
    int n = tid >> 6;
    int o = tid & 63;

    float l0 = cvec[0], l1 = cvec[1], l2 = cvec[2], l3 = cvec[3];
    float mx = fmaxf(fmaxf(l0, l1), fmaxf(l2, l3));
    float a0 = __expf(l0 - mx);
    float a1 = __expf(l1 - mx);
    float a2 = __expf(l2 - mx);
    float a3 = __expf(l3 - mx);
    float inv = 1.0f / (a0 + a1 + a2 + a3);

    const float* yb = y + (size_t)n * 256;
    float self = (a0 * yb[o] + a1 * yb[64 + o] + a2 * yb[128 + o] + a3 * yb[192 + o]) * inv;
    float val = (agg[tid] + self) / (deg[n] + 1.0f) + bvec[o];

    if (DO_RELU_STATS) {
        val = fmaxf(val, 0.0f);
        hout[tid] = val;
        __shared__ float s1[256];
        __shared__ float s2[256];
        s1[threadIdx.x] = val;
        s2[threadIdx.x] = val * val;
        __syncthreads();
        if (threadIdx.x < 64) {
            float s = s1[threadIdx.x] + s1[threadIdx.x + 64] +
                      s1[threadIdx.x + 128] + s1[threadIdx.x + 192];
            float q = s2[threadIdx.x] + s2[threadIdx.x + 64] +
                      s2[threadIdx.x + 128] + s2[threadIdx.x + 192];
            atomicAdd(&stats[threadIdx.x], s);
            atomicAdd(&stats[64 + threadIdx.x], q);
        }
    } else {
        hout[tid] = val;
    }
}

// ---------------------------------------------------------------------------
// BatchNorm apply (training-mode biased stats), in place.
// ---------------------------------------------------------------------------
__global__ __launch_bounds__(256) void bn_kernel(float* __restrict__ h,
                                                 const float* __restrict__ stats,
                                                 const float* __restrict__ g,
                                                 const float* __restrict__ bt) {
    int tid = blockIdx.x * 256 + threadIdx.x;
    int o = tid & 63;
    const float invN = 1.0f / (float)NN;
    float mu = stats[o] * invN;
    float var = stats[64 + o] * invN - mu * mu;
    float sc = rsqrtf(var + BN_EPS) * g[o];
    h[tid] = (h[tid] - mu) * sc + bt[o];
}

extern "C" void kernel_launch(void* const* d_in, const int* in_sizes, int n_in,
                              void* d_out, int out_size, void* d_ws, size_t ws_size,
                              hipStream_t stream) {
    const float* x = (const float*)d_in[0];
    const void* ei = d_in[1];
    const float* W0 = (const float*)d_in[2];
    const float* U0 = (const float*)d_in[3];
    const float* c0 = (const float*)d_in[4];
    const float* b0 = (const float*)d_in[5];
    const float* g0 = (const float*)d_in[6];
    const float* bt0 = (const float*)d_in[7];
    const float* W1 = (const float*)d_in[8];
    const float* U1 = (const float*)d_in[9];
    const float* c1 = (const float*)d_in[10];
    const float* b1 = (const float*)d_in[11];
    const float* g1 = (const float*)d_in[12];
    const float* bt1 = (const float*)d_in[13];
    const float* W2 = (const float*)d_in[14];
    const float* U2 = (const float*)d_in[15];
    const float* c2 = (const float*)d_in[16];
    const float* b2 = (const float*)d_in[17];

    float* ws = (float*)d_ws;
    float* wt = ws;                        // 3 * 16384
    float* y = wt + 3 * 16384;             // NN*256
    float* p = y + (size_t)NN * 256;       // NN*4
    float* agg = p + (size_t)NN * 4;       // NN*64
    float* h1 = agg + (size_t)NN * 64;     // NN*64
    float* h2 = h1 + (size_t)NN * 64;      // NN*64
    float* stats = h2 + (size_t)NN * 64;   // 128
    float* deg = stats + 128;              // NN
    int* flag = (int*)(deg + NN);          // 1

    const int TB = 256;
    const int tfBlocks = (NN / 4) * 64 / TB;         // 1875 exact (7500 waves)
    const int pBlocks = (NN * NH + TB - 1) / TB;     // 469
    const int edgeBlocks = NE / 4;                   // 120000 (one wave per edge)
    const int ncBlocks = (NN * CH) / TB;             // 7500 exact
    const int degBlocks = NE / TB;                   // 1875 exact
    const int trBlocks = (3 * 16384 + TB - 1) / TB;  // 192

    detect_kernel<<<1, 64, 0, stream>>>((const unsigned int*)ei, flag);
    transpose_kernel<<<trBlocks, TB, 0, stream>>>(W0, W1, W2, wt);
    hipMemsetAsync(deg, 0, sizeof(float) * NN, stream);
    deg_kernel<<<degBlocks, TB, 0, stream>>>(ei, flag, deg);

    const float4* wt4_0 = reinterpret_cast<const float4*>(wt);
    const float4* wt4_1 = wt4_0 + 4096;
    const float4* wt4_2 = wt4_1 + 4096;

    // ---- layer 0 ----
    transform_kernel<<<tfBlocks, TB, 0, stream>>>(x, wt4_0, y);
    p_kernel<<<pBlocks, TB, 0, stream>>>(x, U0, p);
    hipMemsetAsync(agg, 0, sizeof(float) * (size_t)NN * 64, stream);
    edge_kernel<<<edgeBlocks, TB, 0, stream>>>(ei, flag, p, y, c0, agg);
    hipMemsetAsync(stats, 0, sizeof(float) * 128, stream);
    finalize_kernel<1><<<ncBlocks, TB, 0, stream>>>(agg, deg, y, c0, b0, h1, stats);
    bn_kernel<<<ncBlocks, TB, 0, stream>>>(h1, stats, g0, bt0);

    // ---- layer 1 ----
    transform_kernel<<<tfBlocks, TB, 0, stream>>>(h1, wt4_1, y);
    p_kernel<<<pBlocks, TB, 0, stream>>>(h1, U1, p);
    hipMemsetAsync(agg, 0, sizeof(float) * (size_t)NN * 64, stream);
    edge_kernel<<<edgeBlocks, TB, 0, stream>>>(ei, flag, p, y, c1, agg);
    hipMemsetAsync(stats, 0, sizeof(float) * 128, stream);
    finalize_kernel<1><<<ncBlocks, TB, 0, stream>>>(agg, deg, y, c1, b1, h2, stats);
    bn_kernel<<<ncBlocks, TB, 0, stream>>>(h2, stats, g1, bt1);

    // ---- layer 2 ----
    transform_kernel<<<tfBlocks, TB, 0, stream>>>(h2, wt4_2, y);
    p_kernel<<<pBlocks, TB, 0, stream>>>(h2, U2, p);
    hipMemsetAsync(agg, 0, sizeof(float) * (size_t)NN * 64, stream);
    edge_kernel<<<edgeBlocks, TB, 0, stream>>>(ei, flag, p, y, c2, agg);
    finalize_kernel<0><<<ncBlocks, TB, 0, stream>>>(agg, deg, y, c2, b2, (float*)d_out, nullptr);
}

// Round 3
// 685.914 us; speedup vs baseline: 2.1501x; 1.4906x over previous
//
#include <hip/hip_runtime.h>

#define NN 30000
#define NE 480000
#define CH 64
#define NH 4
#define BN_EPS 1e-5f
#define NBLK 7500   // NN*CH/256 finalize blocks

// ---------------------------------------------------------------------------
// Detect whether edge_index is stored as int64 (all odd 32-bit words zero)
// or int32. Writes flag (1 = int64) into ws.
// ---------------------------------------------------------------------------
__global__ __launch_bounds__(64) void detect_kernel(const unsigned int* __restrict__ ei,
                                                    int* __restrict__ flag) {
    if (threadIdx.x == 0 && blockIdx.x == 0) {
        int all0 = 1;
        for (int i = 0; i < 64; ++i) {
            if (ei[2 * i + 1] != 0u) all0 = 0;
        }
        *flag = all0;
    }
}

__device__ __forceinline__ int load_idx(const void* ei, int is64, int pos) {
    if (is64) return (int)((const long long*)ei)[pos];
    return ((const int*)ei)[pos];
}

// ---------------------------------------------------------------------------
// Degree of each dst node (real edges only; self loop added in finalize).
// ---------------------------------------------------------------------------
__global__ __launch_bounds__(256) void deg_kernel(const void* __restrict__ ei,
                                                  const int* __restrict__ flag,
                                                  float* __restrict__ deg) {
    int e = blockIdx.x * 256 + threadIdx.x;
    if (e >= NE) return;
    int is64 = *flag;
    int d = load_idx(ei, is64, NE + e);
    atomicAdd(&deg[d], 1.0f);
}

// ---------------------------------------------------------------------------
// One-shot transpose of the three W matrices into wt4 layout:
//   wt4[layer][(k*64 + l)*4 + m] = W_layer[(m*64 + l)*64 + k]
// ---------------------------------------------------------------------------
__global__ __launch_bounds__(256) void transpose_kernel(const float* __restrict__ W0,
                                                        const float* __restrict__ W1,
                                                        const float* __restrict__ W2,
                                                        float* __restrict__ wt) {
    int t = blockIdx.x * 256 + threadIdx.x;      // 3 * 16384 threads
    if (t >= 3 * 16384) return;
    int layer = t / 16384;
    int r = t & 16383;
    int m = r & 3;
    int l = (r >> 2) & 63;
    int k = r >> 8;
    const float* W = (layer == 0) ? W0 : (layer == 1) ? W1 : W2;
    wt[t] = W[(m * 64 + l) * 64 + k];
}

// ---------------------------------------------------------------------------
// Node transform: y[n, 0..255] = h[n,:] @ W^T
// One wave per 4 nodes; lane = base output channel (computes o = m*64+lane).
// ---------------------------------------------------------------------------
__global__ __launch_bounds__(256) void transform_kernel(const float* __restrict__ h,
                                                        const float4* __restrict__ wt4,
                                                        float* __restrict__ y) {
    int wave = (blockIdx.x * 256 + threadIdx.x) >> 6;  // 0..7499 (exact)
    int lane = threadIdx.x & 63;
    int n0 = wave * 4;
    const float4* h4 = reinterpret_cast<const float4*>(h);

    float acc[4][4];
#pragma unroll
    for (int j = 0; j < 4; ++j)
#pragma unroll
        for (int m = 0; m < 4; ++m) acc[j][m] = 0.0f;

#pragma unroll 4
    for (int kb = 0; kb < 16; ++kb) {
        float hb[4][4];
#pragma unroll
        for (int j = 0; j < 4; ++j) {
            float4 v = h4[(size_t)(n0 + j) * 16 + kb];
            hb[j][0] = v.x; hb[j][1] = v.y; hb[j][2] = v.z; hb[j][3] = v.w;
        }
#pragma unroll
        for (int kk = 0; kk < 4; ++kk) {
            float4 wv = wt4[(size_t)(kb * 4 + kk) * 64 + lane];
#pragma unroll
            for (int j = 0; j < 4; ++j) {
                acc[j][0] += hb[j][kk] * wv.x;
                acc[j][1] += hb[j][kk] * wv.y;
                acc[j][2] += hb[j][kk] * wv.z;
                acc[j][3] += hb[j][kk] * wv.w;
            }
        }
    }
#pragma unroll
    for (int j = 0; j < 4; ++j)
#pragma unroll
        for (int m = 0; m < 4; ++m)
            y[(size_t)(n0 + j) * 256 + m * 64 + lane] = acc[j][m];
}

// ---------------------------------------------------------------------------
// p[n, m] = h[n,:] @ U[m,:]   — thread per (node, head)
// ---------------------------------------------------------------------------
__global__ __launch_bounds__(256) void p_kernel(const float* __restrict__ h,
                                                const float* __restrict__ U,
                                                float* __restrict__ p) {
    int t = blockIdx.x * 256 + threadIdx.x;
    if (t >= NN * NH) return;
    int n = t >> 2;
    int m = t & 3;
    const float4* h4 = reinterpret_cast<const float4*>(h) + (size_t)n * 16;
    const float4* U4 = reinterpret_cast<const float4*>(U) + (size_t)m * 16;
    float acc = 0.0f;
#pragma unroll
    for (int j = 0; j < 16; ++j) {
        float4 hv = h4[j];
        float4 uv = U4[j];
        acc += hv.x * uv.x + hv.y * uv.y + hv.z * uv.z + hv.w * uv.w;
    }
    p[t] = acc;
}

// ---------------------------------------------------------------------------
// Edge kernel: one wave per edge, lane = output channel.
// ---------------------------------------------------------------------------
__global__ __launch_bounds__(256) void edge_kernel(const void* __restrict__ ei,
                                                   const int* __restrict__ flag,
                                                   const float* __restrict__ p,
                                                   const float* __restrict__ y,
                                                   const float* __restrict__ cvec,
                                                   float* __restrict__ agg) {
    int e = blockIdx.x * 4 + (threadIdx.x >> 6);
    int lane = threadIdx.x & 63;
    if (e >= NE) return;
    int is64 = *flag;
    int s = load_idx(ei, is64, e);
    int d = load_idx(ei, is64, NE + e);

    float4 ps = *reinterpret_cast<const float4*>(p + (size_t)s * 4);
    float4 pd = *reinterpret_cast<const float4*>(p + (size_t)d * 4);
    float l0 = pd.x - ps.x + cvec[0];
    float l1 = pd.y - ps.y + cvec[1];
    float l2 = pd.z - ps.z + cvec[2];
    float l3 = pd.w - ps.w + cvec[3];
    float mx = fmaxf(fmaxf(l0, l1), fmaxf(l2, l3));
    float a0 = __expf(l0 - mx);
    float a1 = __expf(l1 - mx);
    float a2 = __expf(l2 - mx);
    float a3 = __expf(l3 - mx);
    float inv = 1.0f / (a0 + a1 + a2 + a3);

    const float* yb = y + (size_t)s * 256;
    float msg = (a0 * yb[lane] + a1 * yb[64 + lane] +
                 a2 * yb[128 + lane] + a3 * yb[192 + lane]) * inv;
    atomicAdd(&agg[(size_t)d * 64 + lane], msg);
}

// ---------------------------------------------------------------------------
// Finalize: add self-loop message, /(deg+1), +bias. Optionally ReLU and
// write per-block BN partial sums (NO same-address atomics).
// partial layout: partial[block*128 + slot], slot 0..63 = sum, 64..127 = sumsq.
// ---------------------------------------------------------------------------
template <int DO_RELU_STATS>
__global__ __launch_bounds__(256) void finalize_kernel(const float* __restrict__ agg,
                                                       const float* __restrict__ deg,
                                                       const float* __restrict__ y,
                                                       const float* __restrict__ cvec,
                                                       const float* __restrict__ bvec,
                                                       float* __restrict__ hout,
                                                       float* __restrict__ partial) {
    int tid = blockIdx.x * 256 + threadIdx.x;
    int n = tid >> 6;
    int o = tid & 63;

    float l0 = cvec[0], l1 = cvec[1], l2 = cvec[2], l3 = cvec[3];
    float mx = fmaxf(fmaxf(l0, l1), fmaxf(l2, l3));
    float a0 = __expf(l0 - mx);
    float a1 = __expf(l1 - mx);
    float a2 = __expf(l2 - mx);
    float a3 = __expf(l3 - mx);
    float inv = 1.0f / (a0 + a1 + a2 + a3);

    const float* yb = y + (size_t)n * 256;
    float self = (a0 * yb[o] + a1 * yb[64 + o] + a2 * yb[128 + o] + a3 * yb[192 + o]) * inv;
    float val = (agg[tid] + self) / (deg[n] + 1.0f) + bvec[o];

    if (DO_RELU_STATS) {
        val = fmaxf(val, 0.0f);
        hout[tid] = val;
        __shared__ float s1[256];
        __shared__ float s2[256];
        s1[threadIdx.x] = val;
        s2[threadIdx.x] = val * val;
        __syncthreads();
        if (threadIdx.x < 64) {
            float s = s1[threadIdx.x] + s1[threadIdx.x + 64] +
                      s1[threadIdx.x + 128] + s1[threadIdx.x + 192];
            float q = s2[threadIdx.x] + s2[threadIdx.x + 64] +
                      s2[threadIdx.x + 128] + s2[threadIdx.x + 192];
            partial[blockIdx.x * 128 + threadIdx.x] = s;
            partial[blockIdx.x * 128 + 64 + threadIdx.x] = q;
        }
    } else {
        hout[tid] = val;
    }
}

// ---------------------------------------------------------------------------
// Reduce per-block partials -> stats[128]. One block per slot.
// partial is L2-resident (3.8 MB); strided gathers are fully parallel.
// ---------------------------------------------------------------------------
__global__ __launch_bounds__(256) void reduce_kernel(const float* __restrict__ partial,
                                                     float* __restrict__ stats) {
    int slot = blockIdx.x;           // 0..127
    float acc = 0.0f;
    for (int j = threadIdx.x; j < NBLK; j += 256)
        acc += partial[(size_t)j * 128 + slot];
    __shared__ float sm[256];
    sm[threadIdx.x] = acc;
    __syncthreads();
    for (int off = 128; off > 0; off >>= 1) {
        if (threadIdx.x < off) sm[threadIdx.x] += sm[threadIdx.x + off];
        __syncthreads();
    }
    if (threadIdx.x == 0) stats[slot] = sm[0];
}

// ---------------------------------------------------------------------------
// BatchNorm apply (training-mode biased stats), in place.
// ---------------------------------------------------------------------------
__global__ __launch_bounds__(256) void bn_kernel(float* __restrict__ h,
                                                 const float* __restrict__ stats,
                                                 const float* __restrict__ g,
                                                 const float* __restrict__ bt) {
    int tid = blockIdx.x * 256 + threadIdx.x;
    int o = tid & 63;
    const float invN = 1.0f / (float)NN;
    float mu = stats[o] * invN;
    float var = stats[64 + o] * invN - mu * mu;
    float sc = rsqrtf(var + BN_EPS) * g[o];
    h[tid] = (h[tid] - mu) * sc + bt[o];
}

extern "C" void kernel_launch(void* const* d_in, const int* in_sizes, int n_in,
                              void* d_out, int out_size, void* d_ws, size_t ws_size,
                              hipStream_t stream) {
    const float* x = (const float*)d_in[0];
    const void* ei = d_in[1];
    const float* W0 = (const float*)d_in[2];
    const float* U0 = (const float*)d_in[3];
    const float* c0 = (const float*)d_in[4];
    const float* b0 = (const float*)d_in[5];
    const float* g0 = (const float*)d_in[6];
    const float* bt0 = (const float*)d_in[7];
    const float* W1 = (const float*)d_in[8];
    const float* U1 = (const float*)d_in[9];
    const float* c1 = (const float*)d_in[10];
    const float* b1 = (const float*)d_in[11];
    const float* g1 = (const float*)d_in[12];
    const float* bt1 = (const float*)d_in[13];
    const float* W2 = (const float*)d_in[14];
    const float* U2 = (const float*)d_in[15];
    const float* c2 = (const float*)d_in[16];
    const float* b2 = (const float*)d_in[17];

    float* ws = (float*)d_ws;
    float* wt = ws;                          // 3 * 16384
    float* y = wt + 3 * 16384;               // NN*256
    float* p = y + (size_t)NN * 256;         // NN*4
    float* agg = p + (size_t)NN * 4;         // NN*64
    float* h1 = agg + (size_t)NN * 64;       // NN*64
    float* h2 = h1 + (size_t)NN * 64;        // NN*64
    float* stats = h2 + (size_t)NN * 64;     // 128
    float* deg = stats + 128;                // NN
    float* partial = deg + NN;               // NBLK*128
    int* flag = (int*)(partial + (size_t)NBLK * 128);  // 1

    const int TB = 256;
    const int tfBlocks = (NN / 4) * 64 / TB;         // 1875 exact (7500 waves)
    const int pBlocks = (NN * NH + TB - 1) / TB;     // 469
    const int edgeBlocks = NE / 4;                   // 120000 (one wave per edge)
    const int ncBlocks = (NN * CH) / TB;             // 7500 exact
    const int degBlocks = NE / TB;                   // 1875 exact
    const int trBlocks = (3 * 16384 + TB - 1) / TB;  // 192

    detect_kernel<<<1, 64, 0, stream>>>((const unsigned int*)ei, flag);
    transpose_kernel<<<trBlocks, TB, 0, stream>>>(W0, W1, W2, wt);
    hipMemsetAsync(deg, 0, sizeof(float) * NN, stream);
    deg_kernel<<<degBlocks, TB, 0, stream>>>(ei, flag, deg);

    const float4* wt4_0 = reinterpret_cast<const float4*>(wt);
    const float4* wt4_1 = wt4_0 + 4096;
    const float4* wt4_2 = wt4_1 + 4096;

    // ---- layer 0 ----
    transform_kernel<<<tfBlocks, TB, 0, stream>>>(x, wt4_0, y);
    p_kernel<<<pBlocks, TB, 0, stream>>>(x, U0, p);
    hipMemsetAsync(agg, 0, sizeof(float) * (size_t)NN * 64, stream);
    edge_kernel<<<edgeBlocks, TB, 0, stream>>>(ei, flag, p, y, c0, agg);
    finalize_kernel<1><<<ncBlocks, TB, 0, stream>>>(agg, deg, y, c0, b0, h1, partial);
    reduce_kernel<<<128, TB, 0, stream>>>(partial, stats);
    bn_kernel<<<ncBlocks, TB, 0, stream>>>(h1, stats, g0, bt0);

    // ---- layer 1 ----
    transform_kernel<<<tfBlocks, TB, 0, stream>>>(h1, wt4_1, y);
    p_kernel<<<pBlocks, TB, 0, stream>>>(h1, U1, p);
    hipMemsetAsync(agg, 0, sizeof(float) * (size_t)NN * 64, stream);
    edge_kernel<<<edgeBlocks, TB, 0, stream>>>(ei, flag, p, y, c1, agg);
    finalize_kernel<1><<<ncBlocks, TB, 0, stream>>>(agg, deg, y, c1, b1, h2, partial);
    reduce_kernel<<<128, TB, 0, stream>>>(partial, stats);
    bn_kernel<<<ncBlocks, TB, 0, stream>>>(h2, stats, g1, bt1);

    // ---- layer 2 ----
    transform_kernel<<<tfBlocks, TB, 0, stream>>>(h2, wt4_2, y);
    p_kernel<<<pBlocks, TB, 0, stream>>>(h2, U2, p);
    hipMemsetAsync(agg, 0, sizeof(float) * (size_t)NN * 64, stream);
    edge_kernel<<<edgeBlocks, TB, 0, stream>>>(ei, flag, p, y, c2, agg);
    finalize_kernel<0><<<ncBlocks, TB, 0, stream>>>(agg, deg, y, c2, b2, (float*)d_out, nullptr);
}

// Round 4
// 574.820 us; speedup vs baseline: 2.5656x; 1.1933x over previous
//
#include <hip/hip_runtime.h>

#define NN 30000
#define NE 480000
#define CH 64
#define NH 4
#define BN_EPS 1e-5f
#define NBLK 7500   // NN/4 fused-kernel blocks (256 thr = 4 waves = 4 nodes)

// ---------------------------------------------------------------------------
// Detect whether edge_index is stored as int64 (all odd 32-bit words zero)
// or int32. Writes flag (1 = int64) into ws.
// ---------------------------------------------------------------------------
__global__ __launch_bounds__(64) void detect_kernel(const unsigned int* __restrict__ ei,
                                                    int* __restrict__ flag) {
    if (threadIdx.x == 0 && blockIdx.x == 0) {
        int all0 = 1;
        for (int i = 0; i < 64; ++i) {
            if (ei[2 * i + 1] != 0u) all0 = 0;
        }
        *flag = all0;
    }
}

__device__ __forceinline__ int load_idx(const void* ei, int is64, int pos) {
    if (is64) return (int)((const long long*)ei)[pos];
    return ((const int*)ei)[pos];
}

// ---------------------------------------------------------------------------
// Histogram of dst degrees (real edges only).
// ---------------------------------------------------------------------------
__global__ __launch_bounds__(256) void hist_kernel(const void* __restrict__ ei,
                                                   const int* __restrict__ flag,
                                                   int* __restrict__ degi) {
    int e = blockIdx.x * 256 + threadIdx.x;
    if (e >= NE) return;
    int is64 = *flag;
    int d = load_idx(ei, is64, NE + e);
    atomicAdd(&degi[d], 1);
}

// ---------------------------------------------------------------------------
// Exclusive prefix sum of degi -> rowptr[0..NN]. Single block of 1024.
// ---------------------------------------------------------------------------
__global__ __launch_bounds__(1024) void scan_kernel(const int* __restrict__ degi,
                                                    int* __restrict__ rowptr) {
    __shared__ int part[1024];
    const int CHUNK = 30;  // 1024*30 = 30720 >= NN
    int t = threadIdx.x;
    int base = t * CHUNK;
    int s = 0;
    for (int i = 0; i < CHUNK; ++i) {
        int idx = base + i;
        if (idx < NN) s += degi[idx];
    }
    part[t] = s;
    __syncthreads();
    for (int off = 1; off < 1024; off <<= 1) {
        int v = (t >= off) ? part[t - off] : 0;
        __syncthreads();
        part[t] += v;
        __syncthreads();
    }
    int run = (t == 0) ? 0 : part[t - 1];
    for (int i = 0; i < CHUNK; ++i) {
        int idx = base + i;
        if (idx < NN) {
            rowptr[idx] = run;
            run += degi[idx];
        }
    }
    if (t == 1023) rowptr[NN] = run;
}

// ---------------------------------------------------------------------------
// Scatter src indices into CSR slots (dst-sorted edge list).
// ---------------------------------------------------------------------------
__global__ __launch_bounds__(256) void scatter_kernel(const void* __restrict__ ei,
                                                      const int* __restrict__ flag,
                                                      const int* __restrict__ rowptr,
                                                      int* __restrict__ cursor,
                                                      int* __restrict__ csr) {
    int e = blockIdx.x * 256 + threadIdx.x;
    if (e >= NE) return;
    int is64 = *flag;
    int s = load_idx(ei, is64, e);
    int d = load_idx(ei, is64, NE + e);
    int pos = rowptr[d] + atomicAdd(&cursor[d], 1);
    csr[pos] = s;
}

// ---------------------------------------------------------------------------
// One-shot transpose of the three W matrices into wt4 layout:
//   wt4[layer][(k*64 + l)*4 + m] = W_layer[(m*64 + l)*64 + k]
// ---------------------------------------------------------------------------
__global__ __launch_bounds__(256) void transpose_kernel(const float* __restrict__ W0,
                                                        const float* __restrict__ W1,
                                                        const float* __restrict__ W2,
                                                        float* __restrict__ wt) {
    int t = blockIdx.x * 256 + threadIdx.x;      // 3 * 16384 threads
    if (t >= 3 * 16384) return;
    int layer = t / 16384;
    int r = t & 16383;
    int m = r & 3;
    int l = (r >> 2) & 63;
    int k = r >> 8;
    const float* W = (layer == 0) ? W0 : (layer == 1) ? W1 : W2;
    wt[t] = W[(m * 64 + l) * 64 + k];
}

// ---------------------------------------------------------------------------
// Node transform: y2[n][o][m] = (h[n,:] @ W^T)[m*64+o]  (heads contiguous)
// One wave per 4 nodes; lane = output channel o; float4 store per node.
// ---------------------------------------------------------------------------
__global__ __launch_bounds__(256) void transform_kernel(const float* __restrict__ h,
                                                        const float4* __restrict__ wt4,
                                                        float4* __restrict__ y4) {
    int wave = (blockIdx.x * 256 + threadIdx.x) >> 6;  // 0..7499 (exact)
    int lane = threadIdx.x & 63;
    int n0 = wave * 4;
    const float4* h4 = reinterpret_cast<const float4*>(h);

    float acc[4][4];
#pragma unroll
    for (int j = 0; j < 4; ++j)
#pragma unroll
        for (int m = 0; m < 4; ++m) acc[j][m] = 0.0f;

#pragma unroll 4
    for (int kb = 0; kb < 16; ++kb) {
        float hb[4][4];
#pragma unroll
        for (int j = 0; j < 4; ++j) {
            float4 v = h4[(size_t)(n0 + j) * 16 + kb];
            hb[j][0] = v.x; hb[j][1] = v.y; hb[j][2] = v.z; hb[j][3] = v.w;
        }
#pragma unroll
        for (int kk = 0; kk < 4; ++kk) {
            float4 wv = wt4[(size_t)(kb * 4 + kk) * 64 + lane];
#pragma unroll
            for (int j = 0; j < 4; ++j) {
                acc[j][0] += hb[j][kk] * wv.x;
                acc[j][1] += hb[j][kk] * wv.y;
                acc[j][2] += hb[j][kk] * wv.z;
                acc[j][3] += hb[j][kk] * wv.w;
            }
        }
    }
#pragma unroll
    for (int j = 0; j < 4; ++j)
        y4[(size_t)(n0 + j) * 64 + lane] =
            make_float4(acc[j][0], acc[j][1], acc[j][2], acc[j][3]);
}

// ---------------------------------------------------------------------------
// p[n, m] = h[n,:] @ U[m,:]   — thread per (node, head)
// ---------------------------------------------------------------------------
__global__ __launch_bounds__(256) void p_kernel(const float* __restrict__ h,
                                                const float* __restrict__ U,
                                                float* __restrict__ p) {
    int t = blockIdx.x * 256 + threadIdx.x;
    if (t >= NN * NH) return;
    int n = t >> 2;
    int m = t & 3;
    const float4* h4 = reinterpret_cast<const float4*>(h) + (size_t)n * 16;
    const float4* U4 = reinterpret_cast<const float4*>(U) + (size_t)m * 16;
    float acc = 0.0f;
#pragma unroll
    for (int j = 0; j < 16; ++j) {
        float4 hv = h4[j];
        float4 uv = U4[j];
        acc += hv.x * uv.x + hv.y * uv.y + hv.z * uv.z + hv.w * uv.w;
    }
    p[t] = acc;
}

// ---------------------------------------------------------------------------
// Per-edge attention-weighted message for this lane's channel.
// ---------------------------------------------------------------------------
__device__ __forceinline__ float edge_msg(float4 ps, float4 pd, float4 cv, float4 v) {
    float l0 = pd.x - ps.x + cv.x;
    float l1 = pd.y - ps.y + cv.y;
    float l2 = pd.z - ps.z + cv.z;
    float l3 = pd.w - ps.w + cv.w;
    float mx = fmaxf(fmaxf(l0, l1), fmaxf(l2, l3));
    float a0 = __expf(l0 - mx);
    float a1 = __expf(l1 - mx);
    float a2 = __expf(l2 - mx);
    float a3 = __expf(l3 - mx);
    float inv = 1.0f / (a0 + a1 + a2 + a3);
    return (a0 * v.x + a1 * v.y + a2 * v.z + a3 * v.w) * inv;
}

// ---------------------------------------------------------------------------
// Fused aggregate: one wave per dst node, lane = output channel.
// Gathers all CSR in-edges (no atomics), adds self-loop, /(deg+1), +bias,
// optional ReLU + per-block BN partials.
// ---------------------------------------------------------------------------
template <int DO_RELU_STATS>
__global__ __launch_bounds__(256) void aggregate_kernel(const int* __restrict__ rowptr,
                                                        const int* __restrict__ csr,
                                                        const float* __restrict__ p,
                                                        const float4* __restrict__ y4,
                                                        const float* __restrict__ cvec,
                                                        const float* __restrict__ bvec,
                                                        float* __restrict__ hout,
                                                        float* __restrict__ partial) {
    int n = (blockIdx.x * 256 + threadIdx.x) >> 6;  // 0..29999 (exact)
    int lane = threadIdx.x & 63;
    const float4* p4 = reinterpret_cast<const float4*>(p);

    float4 cv = make_float4(cvec[0], cvec[1], cvec[2], cvec[3]);
    float4 pd = p4[n];

    int start = rowptr[n];
    int end = rowptr[n + 1];
    float acc = 0.0f;
    int j = start;
    for (; j + 2 <= end; j += 2) {
        int s0 = csr[j];
        int s1 = csr[j + 1];
        float4 q0 = p4[s0];
        float4 q1 = p4[s1];
        float4 v0 = y4[(size_t)s0 * 64 + lane];
        float4 v1 = y4[(size_t)s1 * 64 + lane];
        acc += edge_msg(q0, pd, cv, v0);
        acc += edge_msg(q1, pd, cv, v1);
    }
    if (j < end) {
        int s0 = csr[j];
        float4 q0 = p4[s0];
        float4 v0 = y4[(size_t)s0 * 64 + lane];
        acc += edge_msg(q0, pd, cv, v0);
    }

    // self loop: logits = c (pd - pd + c)
    float4 vself = y4[(size_t)n * 64 + lane];
    acc += edge_msg(pd, pd, cv, vself);

    float val = acc / (float)(end - start + 1) + bvec[lane];

    if (DO_RELU_STATS) {
        val = fmaxf(val, 0.0f);
        hout[(size_t)n * 64 + lane] = val;
        __shared__ float s1m[256];
        __shared__ float s2m[256];
        s1m[threadIdx.x] = val;
        s2m[threadIdx.x] = val * val;
        __syncthreads();
        if (threadIdx.x < 64) {
            float s = s1m[threadIdx.x] + s1m[threadIdx.x + 64] +
                      s1m[threadIdx.x + 128] + s1m[threadIdx.x + 192];
            float q = s2m[threadIdx.x] + s2m[threadIdx.x + 64] +
                      s2m[threadIdx.x + 128] + s2m[threadIdx.x + 192];
            partial[blockIdx.x * 128 + threadIdx.x] = s;
            partial[blockIdx.x * 128 + 64 + threadIdx.x] = q;
        }
    } else {
        hout[(size_t)n * 64 + lane] = val;
    }
}

// ---------------------------------------------------------------------------
// Reduce per-block partials -> stats[128]. One block per slot.
// ---------------------------------------------------------------------------
__global__ __launch_bounds__(256) void reduce_kernel(const float* __restrict__ partial,
                                                     float* __restrict__ stats) {
    int slot = blockIdx.x;           // 0..127
    float acc = 0.0f;
    for (int j = threadIdx.x; j < NBLK; j += 256)
        acc += partial[(size_t)j * 128 + slot];
    __shared__ float sm[256];
    sm[threadIdx.x] = acc;
    __syncthreads();
    for (int off = 128; off > 0; off >>= 1) {
        if (threadIdx.x < off) sm[threadIdx.x] += sm[threadIdx.x + off];
        __syncthreads();
    }
    if (threadIdx.x == 0) stats[slot] = sm[0];
}

// ---------------------------------------------------------------------------
// BatchNorm apply (training-mode biased stats), in place.
// ---------------------------------------------------------------------------
__global__ __launch_bounds__(256) void bn_kernel(float* __restrict__ h,
                                                 const float* __restrict__ stats,
                                                 const float* __restrict__ g,
                                                 const float* __restrict__ bt) {
    int tid = blockIdx.x * 256 + threadIdx.x;
    int o = tid & 63;
    const float invN = 1.0f / (float)NN;
    float mu = stats[o] * invN;
    float var = stats[64 + o] * invN - mu * mu;
    float sc = rsqrtf(var + BN_EPS) * g[o];
    h[tid] = (h[tid] - mu) * sc + bt[o];
}

extern "C" void kernel_launch(void* const* d_in, const int* in_sizes, int n_in,
                              void* d_out, int out_size, void* d_ws, size_t ws_size,
                              hipStream_t stream) {
    const float* x = (const float*)d_in[0];
    const void* ei = d_in[1];
    const float* W0 = (const float*)d_in[2];
    const float* U0 = (const float*)d_in[3];
    const float* c0 = (const float*)d_in[4];
    const float* b0 = (const float*)d_in[5];
    const float* g0 = (const float*)d_in[6];
    const float* bt0 = (const float*)d_in[7];
    const float* W1 = (const float*)d_in[8];
    const float* U1 = (const float*)d_in[9];
    const float* c1 = (const float*)d_in[10];
    const float* b1 = (const float*)d_in[11];
    const float* g1 = (const float*)d_in[12];
    const float* bt1 = (const float*)d_in[13];
    const float* W2 = (const float*)d_in[14];
    const float* U2 = (const float*)d_in[15];
    const float* c2 = (const float*)d_in[16];
    const float* b2 = (const float*)d_in[17];

    float* ws = (float*)d_ws;
    float* wt = ws;                          // 3 * 16384
    float* y = wt + 3 * 16384;               // NN*256
    float* p = y + (size_t)NN * 256;         // NN*4
    float* h1 = p + (size_t)NN * 4;          // NN*64
    float* h2 = h1 + (size_t)NN * 64;        // NN*64
    float* stats = h2 + (size_t)NN * 64;     // 128
    float* partial = stats + 128;            // NBLK*128
    int* degi = (int*)(partial + (size_t)NBLK * 128);  // NN
    int* rowptr = degi + NN;                 // NN+1
    int* cursor = rowptr + NN + 1;           // NN
    int* csr = cursor + NN;                  // NE
    int* flag = csr + NE;                    // 1

    float4* y4 = reinterpret_cast<float4*>(y);

    const int TB = 256;
    const int tfBlocks = (NN / 4) * 64 / TB;         // 1875 exact (7500 waves)
    const int pBlocks = (NN * NH + TB - 1) / TB;     // 469
    const int aggBlocks = NBLK;                      // 7500 (wave per node)
    const int ncBlocks = (NN * CH) / TB;             // 7500 exact
    const int eBlocks = NE / TB;                     // 1875 exact
    const int trBlocks = (3 * 16384 + TB - 1) / TB;  // 192

    // ---- one-shot prep: dtype flag, W transpose, CSR by dst ----
    detect_kernel<<<1, 64, 0, stream>>>((const unsigned int*)ei, flag);
    transpose_kernel<<<trBlocks, TB, 0, stream>>>(W0, W1, W2, wt);
    hipMemsetAsync(degi, 0, sizeof(int) * NN, stream);
    hipMemsetAsync(cursor, 0, sizeof(int) * NN, stream);
    hist_kernel<<<eBlocks, TB, 0, stream>>>(ei, flag, degi);
    scan_kernel<<<1, 1024, 0, stream>>>(degi, rowptr);
    scatter_kernel<<<eBlocks, TB, 0, stream>>>(ei, flag, rowptr, cursor, csr);

    const float4* wt4_0 = reinterpret_cast<const float4*>(wt);
    const float4* wt4_1 = wt4_0 + 4096;
    const float4* wt4_2 = wt4_1 + 4096;

    // ---- layer 0 ----
    transform_kernel<<<tfBlocks, TB, 0, stream>>>(x, wt4_0, y4);
    p_kernel<<<pBlocks, TB, 0, stream>>>(x, U0, p);
    aggregate_kernel<1><<<aggBlocks, TB, 0, stream>>>(rowptr, csr, p, y4, c0, b0, h1, partial);
    reduce_kernel<<<128, TB, 0, stream>>>(partial, stats);
    bn_kernel<<<ncBlocks, TB, 0, stream>>>(h1, stats, g0, bt0);

    // ---- layer 1 ----
    transform_kernel<<<tfBlocks, TB, 0, stream>>>(h1, wt4_1, y4);
    p_kernel<<<pBlocks, TB, 0, stream>>>(h1, U1, p);
    aggregate_kernel<1><<<aggBlocks, TB, 0, stream>>>(rowptr, csr, p, y4, c1, b1, h2, partial);
    reduce_kernel<<<128, TB, 0, stream>>>(partial, stats);
    bn_kernel<<<ncBlocks, TB, 0, stream>>>(h2, stats, g1, bt1);

    // ---- layer 2 ----
    transform_kernel<<<tfBlocks, TB, 0, stream>>>(h2, wt4_2, y4);
    p_kernel<<<pBlocks, TB, 0, stream>>>(h2, U2, p);
    aggregate_kernel<0><<<aggBlocks, TB, 0, stream>>>(rowptr, csr, p, y4, c2, b2, (float*)d_out, nullptr);
}

// Round 6
// 491.047 us; speedup vs baseline: 3.0033x; 1.1706x over previous
//
#include <hip/hip_runtime.h>

#define NN 30000
#define NE 480000
#define CH 64
#define NH 4
#define BN_EPS 1e-5f
#define NBLK 7500   // NN/4 aggregate blocks (256 thr = 4 waves = 4 nodes)

// ---------------------------------------------------------------------------
// bf16 helpers (RNE pack, cheap unpack)
// ---------------------------------------------------------------------------
__device__ __forceinline__ unsigned short f2bf(float x) {
    unsigned int u = __float_as_uint(x);
    return (unsigned short)((u + 0x7fffu + ((u >> 16) & 1u)) >> 16);
}
__device__ __forceinline__ float bf2f(unsigned short h) {
    return __uint_as_float(((unsigned int)h) << 16);
}

// ---------------------------------------------------------------------------
// Detect whether edge_index is stored as int64 (all odd 32-bit words zero)
// or int32. Writes flag (1 = int64) into ws.
// ---------------------------------------------------------------------------
__global__ __launch_bounds__(64) void detect_kernel(const unsigned int* __restrict__ ei,
                                                    int* __restrict__ flag) {
    if (threadIdx.x == 0 && blockIdx.x == 0) {
        int all0 = 1;
        for (int i = 0; i < 64; ++i) {
            if (ei[2 * i + 1] != 0u) all0 = 0;
        }
        *flag = all0;
    }
}

__device__ __forceinline__ int load_idx(const void* ei, int is64, int pos) {
    if (is64) return (int)((const long long*)ei)[pos];
    return ((const int*)ei)[pos];
}

// ---------------------------------------------------------------------------
// Histogram of dst degrees (real edges only).
// ---------------------------------------------------------------------------
__global__ __launch_bounds__(256) void hist_kernel(const void* __restrict__ ei,
                                                   const int* __restrict__ flag,
                                                   int* __restrict__ degi) {
    int e = blockIdx.x * 256 + threadIdx.x;
    if (e >= NE) return;
    int is64 = *flag;
    int d = load_idx(ei, is64, NE + e);
    atomicAdd(&degi[d], 1);
}

// ---------------------------------------------------------------------------
// Exclusive prefix sum of degi -> rowptr[0..NN]. Single block of 1024.
// ---------------------------------------------------------------------------
__global__ __launch_bounds__(1024) void scan_kernel(const int* __restrict__ degi,
                                                    int* __restrict__ rowptr) {
    __shared__ int part[1024];
    const int CHUNK = 30;  // 1024*30 = 30720 >= NN
    int t = threadIdx.x;
    int base = t * CHUNK;
    int s = 0;
    for (int i = 0; i < CHUNK; ++i) {
        int idx = base + i;
        if (idx < NN) s += degi[idx];
    }
    part[t] = s;
    __syncthreads();
    for (int off = 1; off < 1024; off <<= 1) {
        int v = (t >= off) ? part[t - off] : 0;
        __syncthreads();
        part[t] += v;
        __syncthreads();
    }
    int run = (t == 0) ? 0 : part[t - 1];
    for (int i = 0; i < CHUNK; ++i) {
        int idx = base + i;
        if (idx < NN) {
            rowptr[idx] = run;
            run += degi[idx];
        }
    }
    if (t == 1023) rowptr[NN] = run;
}

// ---------------------------------------------------------------------------
// Scatter src indices into CSR slots (dst-sorted edge list).
// ---------------------------------------------------------------------------
__global__ __launch_bounds__(256) void scatter_kernel(const void* __restrict__ ei,
                                                      const int* __restrict__ flag,
                                                      const int* __restrict__ rowptr,
                                                      int* __restrict__ cursor,
                                                      int* __restrict__ csr) {
    int e = blockIdx.x * 256 + threadIdx.x;
    if (e >= NE) return;
    int is64 = *flag;
    int s = load_idx(ei, is64, e);
    int d = load_idx(ei, is64, NE + e);
    int pos = rowptr[d] + atomicAdd(&cursor[d], 1);
    csr[pos] = s;
}

// ---------------------------------------------------------------------------
// One-shot transpose of the three W matrices into wt4 layout:
//   wt4[layer][(k*64 + l)*4 + m] = W_layer[(m*64 + l)*64 + k]
// ---------------------------------------------------------------------------
__global__ __launch_bounds__(256) void transpose_kernel(const float* __restrict__ W0,
                                                        const float* __restrict__ W1,
                                                        const float* __restrict__ W2,
                                                        float* __restrict__ wt) {
    int t = blockIdx.x * 256 + threadIdx.x;      // 3 * 16384 threads
    if (t >= 3 * 16384) return;
    int layer = t / 16384;
    int r = t & 16383;
    int m = r & 3;
    int l = (r >> 2) & 63;
    int k = r >> 8;
    const float* W = (layer == 0) ? W0 : (layer == 1) ? W1 : W2;
    wt[t] = W[(m * 64 + l) * 64 + k];
}

// ---------------------------------------------------------------------------
// Node transform: y2[n][o] = bf16x4 of (h[n,:] @ W^T)[{0,1,2,3}*64+o]
// One wave per 4 nodes; lane = output channel o; 8 B store per node.
// ---------------------------------------------------------------------------
__global__ __launch_bounds__(256) void transform_kernel(const float* __restrict__ h,
                                                        const float4* __restrict__ wt4,
                                                        ushort4* __restrict__ y2) {
    int wave = (blockIdx.x * 256 + threadIdx.x) >> 6;  // 0..7499 (exact)
    int lane = threadIdx.x & 63;
    int n0 = wave * 4;
    const float4* h4 = reinterpret_cast<const float4*>(h);

    float acc[4][4];
#pragma unroll
    for (int j = 0; j < 4; ++j)
#pragma unroll
        for (int m = 0; m < 4; ++m) acc[j][m] = 0.0f;

#pragma unroll 4
    for (int kb = 0; kb < 16; ++kb) {
        float hb[4][4];
#pragma unroll
        for (int j = 0; j < 4; ++j) {
            float4 v = h4[(size_t)(n0 + j) * 16 + kb];
            hb[j][0] = v.x; hb[j][1] = v.y; hb[j][2] = v.z; hb[j][3] = v.w;
        }
#pragma unroll
        for (int kk = 0; kk < 4; ++kk) {
            float4 wv = wt4[(size_t)(kb * 4 + kk) * 64 + lane];
#pragma unroll
            for (int j = 0; j < 4; ++j) {
                acc[j][0] += hb[j][kk] * wv.x;
                acc[j][1] += hb[j][kk] * wv.y;
                acc[j][2] += hb[j][kk] * wv.z;
                acc[j][3] += hb[j][kk] * wv.w;
            }
        }
    }
#pragma unroll
    for (int j = 0; j < 4; ++j) {
        ushort4 o;
        o.x = f2bf(acc[j][0]);
        o.y = f2bf(acc[j][1]);
        o.z = f2bf(acc[j][2]);
        o.w = f2bf(acc[j][3]);
        y2[(size_t)(n0 + j) * 64 + lane] = o;
    }
}

// ---------------------------------------------------------------------------
// p[n, m] = h[n,:] @ U[m,:]   — thread per (node, head)
// ---------------------------------------------------------------------------
__global__ __launch_bounds__(256) void p_kernel(const float* __restrict__ h,
                                                const float* __restrict__ U,
                                                float* __restrict__ p) {
    int t = blockIdx.x * 256 + threadIdx.x;
    if (t >= NN * NH) return;
    int n = t >> 2;
    int m = t & 3;
    const float4* h4 = reinterpret_cast<const float4*>(h) + (size_t)n * 16;
    const float4* U4 = reinterpret_cast<const float4*>(U) + (size_t)m * 16;
    float acc = 0.0f;
#pragma unroll
    for (int j = 0; j < 16; ++j) {
        float4 hv = h4[j];
        float4 uv = U4[j];
        acc += hv.x * uv.x + hv.y * uv.y + hv.z * uv.z + hv.w * uv.w;
    }
    p[t] = acc;
}

// ---------------------------------------------------------------------------
// Per-edge attention-weighted message. pdc = p[dst] + c precomputed.
// Max-subtraction REQUIRED: BN amplifies low-variance channels so |p| can
// reach O(10^2..10^3); un-stabilized exp overflows to inf -> NaN (Round 5).
// ---------------------------------------------------------------------------
__device__ __forceinline__ float edge_msg(float4 pdc, float4 ps, ushort4 w) {
    float l0 = pdc.x - ps.x;
    float l1 = pdc.y - ps.y;
    float l2 = pdc.z - ps.z;
    float l3 = pdc.w - ps.w;
    float mx = fmaxf(fmaxf(l0, l1), fmaxf(l2, l3));
    float e0 = __expf(l0 - mx);
    float e1 = __expf(l1 - mx);
    float e2 = __expf(l2 - mx);
    float e3 = __expf(l3 - mx);
    float inv = 1.0f / (e0 + e1 + e2 + e3);
    return (e0 * bf2f(w.x) + e1 * bf2f(w.y) + e2 * bf2f(w.z) + e3 * bf2f(w.w)) * inv;
}

// ---------------------------------------------------------------------------
// Fused aggregate: one wave per dst node, lane = output channel.
// Gathers all CSR in-edges (no atomics), adds self-loop, /(deg+1), +bias,
// optional ReLU + per-block BN partials.
// ---------------------------------------------------------------------------
template <int DO_RELU_STATS>
__global__ __launch_bounds__(256) void aggregate_kernel(const int* __restrict__ rowptr,
                                                        const int* __restrict__ csr,
                                                        const float* __restrict__ p,
                                                        const ushort4* __restrict__ y2,
                                                        const float* __restrict__ cvec,
                                                        const float* __restrict__ bvec,
                                                        float* __restrict__ hout,
                                                        float* __restrict__ partial) {
    int n = (blockIdx.x * 256 + threadIdx.x) >> 6;  // 0..29999 (exact)
    int lane = threadIdx.x & 63;
    const float4* p4 = reinterpret_cast<const float4*>(p);

    float4 pd = p4[n];
    float4 pdc = make_float4(pd.x + cvec[0], pd.y + cvec[1],
                             pd.z + cvec[2], pd.w + cvec[3]);

    int start = rowptr[n];
    int end = rowptr[n + 1];
    float acc = 0.0f;
    int j = start;
    for (; j + 4 <= end; j += 4) {
        int s0 = csr[j];
        int s1 = csr[j + 1];
        int s2 = csr[j + 2];
        int s3 = csr[j + 3];
        float4 q0 = p4[s0];
        float4 q1 = p4[s1];
        float4 q2 = p4[s2];
        float4 q3 = p4[s3];
        ushort4 w0 = y2[(size_t)s0 * 64 + lane];
        ushort4 w1 = y2[(size_t)s1 * 64 + lane];
        ushort4 w2 = y2[(size_t)s2 * 64 + lane];
        ushort4 w3 = y2[(size_t)s3 * 64 + lane];
        acc += edge_msg(pdc, q0, w0);
        acc += edge_msg(pdc, q1, w1);
        acc += edge_msg(pdc, q2, w2);
        acc += edge_msg(pdc, q3, w3);
    }
    for (; j < end; ++j) {
        int s0 = csr[j];
        float4 q0 = p4[s0];
        ushort4 w0 = y2[(size_t)s0 * 64 + lane];
        acc += edge_msg(pdc, q0, w0);
    }

    // self loop: logits = c (ps = pd)
    ushort4 wself = y2[(size_t)n * 64 + lane];
    acc += edge_msg(pdc, pd, wself);

    float val = acc / (float)(end - start + 1) + bvec[lane];

    if (DO_RELU_STATS) {
        val = fmaxf(val, 0.0f);
        hout[(size_t)n * 64 + lane] = val;
        __shared__ float s1m[256];
        __shared__ float s2m[256];
        s1m[threadIdx.x] = val;
        s2m[threadIdx.x] = val * val;
        __syncthreads();
        if (threadIdx.x < 64) {
            float s = s1m[threadIdx.x] + s1m[threadIdx.x + 64] +
                      s1m[threadIdx.x + 128] + s1m[threadIdx.x + 192];
            float q = s2m[threadIdx.x] + s2m[threadIdx.x + 64] +
                      s2m[threadIdx.x + 128] + s2m[threadIdx.x + 192];
            partial[blockIdx.x * 128 + threadIdx.x] = s;
            partial[blockIdx.x * 128 + 64 + threadIdx.x] = q;
        }
    } else {
        hout[(size_t)n * 64 + lane] = val;
    }
}

// ---------------------------------------------------------------------------
// Reduce per-block partials -> stats[128]. One block per slot.
// ---------------------------------------------------------------------------
__global__ __launch_bounds__(256) void reduce_kernel(const float* __restrict__ partial,
                                                     float* __restrict__ stats) {
    int slot = blockIdx.x;           // 0..127
    float acc = 0.0f;
    for (int j = threadIdx.x; j < NBLK; j += 256)
        acc += partial[(size_t)j * 128 + slot];
    __shared__ float sm[256];
    sm[threadIdx.x] = acc;
    __syncthreads();
    for (int off = 128; off > 0; off >>= 1) {
        if (threadIdx.x < off) sm[threadIdx.x] += sm[threadIdx.x + off];
        __syncthreads();
    }
    if (threadIdx.x == 0) stats[slot] = sm[0];
}

// ---------------------------------------------------------------------------
// BatchNorm apply (training-mode biased stats), in place.
// ---------------------------------------------------------------------------
__global__ __launch_bounds__(256) void bn_kernel(float* __restrict__ h,
                                                 const float* __restrict__ stats,
                                                 const float* __restrict__ g,
                                                 const float* __restrict__ bt) {
    int tid = blockIdx.x * 256 + threadIdx.x;
    int o = tid & 63;
    const float invN = 1.0f / (float)NN;
    float mu = stats[o] * invN;
    float var = stats[64 + o] * invN - mu * mu;
    float sc = rsqrtf(var + BN_EPS) * g[o];
    h[tid] = (h[tid] - mu) * sc + bt[o];
}

extern "C" void kernel_launch(void* const* d_in, const int* in_sizes, int n_in,
                              void* d_out, int out_size, void* d_ws, size_t ws_size,
                              hipStream_t stream) {
    const float* x = (const float*)d_in[0];
    const void* ei = d_in[1];
    const float* W0 = (const float*)d_in[2];
    const float* U0 = (const float*)d_in[3];
    const float* c0 = (const float*)d_in[4];
    const float* b0 = (const float*)d_in[5];
    const float* g0 = (const float*)d_in[6];
    const float* bt0 = (const float*)d_in[7];
    const float* W1 = (const float*)d_in[8];
    const float* U1 = (const float*)d_in[9];
    const float* c1 = (const float*)d_in[10];
    const float* b1 = (const float*)d_in[11];
    const float* g1 = (const float*)d_in[12];
    const float* bt1 = (const float*)d_in[13];
    const float* W2 = (const float*)d_in[14];
    const float* U2 = (const float*)d_in[15];
    const float* c2 = (const float*)d_in[16];
    const float* b2 = (const float*)d_in[17];

    float* ws = (float*)d_ws;
    float* wt = ws;                                       // 3*16384 floats
    ushort4* y2 = (ushort4*)(wt + 3 * 16384);             // NN*64 ushort4 (15 MB)
    float* p = (float*)((unsigned short*)y2 + (size_t)NN * 256);  // NN*4
    float* h1 = p + (size_t)NN * 4;          // NN*64
    float* h2 = h1 + (size_t)NN * 64;        // NN*64
    float* stats = h2 + (size_t)NN * 64;     // 128
    float* partial = stats + 128;            // NBLK*128
    int* degi = (int*)(partial + (size_t)NBLK * 128);  // NN
    int* rowptr = degi + NN;                 // NN+1
    int* cursor = rowptr + NN + 1;           // NN
    int* csr = cursor + NN;                  // NE
    int* flag = csr + NE;                    // 1

    const int TB = 256;
    const int tfBlocks = (NN / 4) * 64 / TB;         // 1875 exact (7500 waves)
    const int pBlocks = (NN * NH + TB - 1) / TB;     // 469
    const int aggBlocks = NBLK;                      // 7500 (wave per node)
    const int ncBlocks = (NN * CH) / TB;             // 7500 exact
    const int eBlocks = NE / TB;                     // 1875 exact
    const int trBlocks = (3 * 16384 + TB - 1) / TB;  // 192

    // ---- one-shot prep: dtype flag, W transpose, CSR by dst ----
    detect_kernel<<<1, 64, 0, stream>>>((const unsigned int*)ei, flag);
    transpose_kernel<<<trBlocks, TB, 0, stream>>>(W0, W1, W2, wt);
    hipMemsetAsync(degi, 0, sizeof(int) * NN, stream);
    hipMemsetAsync(cursor, 0, sizeof(int) * NN, stream);
    hist_kernel<<<eBlocks, TB, 0, stream>>>(ei, flag, degi);
    scan_kernel<<<1, 1024, 0, stream>>>(degi, rowptr);
    scatter_kernel<<<eBlocks, TB, 0, stream>>>(ei, flag, rowptr, cursor, csr);

    const float4* wt4_0 = reinterpret_cast<const float4*>(wt);
    const float4* wt4_1 = wt4_0 + 4096;
    const float4* wt4_2 = wt4_1 + 4096;

    // ---- layer 0 ----
    transform_kernel<<<tfBlocks, TB, 0, stream>>>(x, wt4_0, y2);
    p_kernel<<<pBlocks, TB, 0, stream>>>(x, U0, p);
    aggregate_kernel<1><<<aggBlocks, TB, 0, stream>>>(rowptr, csr, p, y2, c0, b0, h1, partial);
    reduce_kernel<<<128, TB, 0, stream>>>(partial, stats);
    bn_kernel<<<ncBlocks, TB, 0, stream>>>(h1, stats, g0, bt0);

    // ---- layer 1 ----
    transform_kernel<<<tfBlocks, TB, 0, stream>>>(h1, wt4_1, y2);
    p_kernel<<<pBlocks, TB, 0, stream>>>(h1, U1, p);
    aggregate_kernel<1><<<aggBlocks, TB, 0, stream>>>(rowptr, csr, p, y2, c1, b1, h2, partial);
    reduce_kernel<<<128, TB, 0, stream>>>(partial, stats);
    bn_kernel<<<ncBlocks, TB, 0, stream>>>(h2, stats, g1, bt1);

    // ---- layer 2 ----
    transform_kernel<<<tfBlocks, TB, 0, stream>>>(h2, wt4_2, y2);
    p_kernel<<<pBlocks, TB, 0, stream>>>(h2, U2, p);
    aggregate_kernel<0><<<aggBlocks, TB, 0, stream>>>(rowptr, csr, p, y2, c2, b2, (float*)d_out, nullptr);
}

// Round 7
// 443.144 us; speedup vs baseline: 3.3280x; 1.1081x over previous
//
#include <hip/hip_runtime.h>

#define NN 30000
#define NE 480000
#define CH 64
#define NH 4
#define BN_EPS 1e-5f
#define NBLK 7500   // NN/4 aggregate blocks (256 thr = 4 waves = 4 nodes)

// ---------------------------------------------------------------------------
// bf16 helpers (RNE pack, cheap unpack)
// ---------------------------------------------------------------------------
__device__ __forceinline__ unsigned short f2bf(float x) {
    unsigned int u = __float_as_uint(x);
    return (unsigned short)((u + 0x7fffu + ((u >> 16) & 1u)) >> 16);
}
__device__ __forceinline__ float bf2f(unsigned short h) {
    return __uint_as_float(((unsigned int)h) << 16);
}

// ---------------------------------------------------------------------------
// Detect int64 vs int32 edge_index (all odd 32-bit words zero => int64).
// ---------------------------------------------------------------------------
__global__ __launch_bounds__(64) void detect_kernel(const unsigned int* __restrict__ ei,
                                                    int* __restrict__ flag) {
    if (threadIdx.x == 0 && blockIdx.x == 0) {
        int all0 = 1;
        for (int i = 0; i < 64; ++i) {
            if (ei[2 * i + 1] != 0u) all0 = 0;
        }
        *flag = all0;
    }
}

__device__ __forceinline__ int load_idx(const void* ei, int is64, int pos) {
    if (is64) return (int)((const long long*)ei)[pos];
    return ((const int*)ei)[pos];
}

// ---------------------------------------------------------------------------
// Histogram of dst degrees (real edges only).
// ---------------------------------------------------------------------------
__global__ __launch_bounds__(256) void hist_kernel(const void* __restrict__ ei,
                                                   const int* __restrict__ flag,
                                                   int* __restrict__ degi) {
    int e = blockIdx.x * 256 + threadIdx.x;
    if (e >= NE) return;
    int is64 = *flag;
    int d = load_idx(ei, is64, NE + e);
    atomicAdd(&degi[d], 1);
}

// ---------------------------------------------------------------------------
// Exclusive prefix sum of degi -> rowptr[0..NN]. Single block of 1024.
// ---------------------------------------------------------------------------
__global__ __launch_bounds__(1024) void scan_kernel(const int* __restrict__ degi,
                                                    int* __restrict__ rowptr) {
    __shared__ int part[1024];
    const int CHUNK = 30;  // 1024*30 = 30720 >= NN
    int t = threadIdx.x;
    int base = t * CHUNK;
    int s = 0;
    for (int i = 0; i < CHUNK; ++i) {
        int idx = base + i;
        if (idx < NN) s += degi[idx];
    }
    part[t] = s;
    __syncthreads();
    for (int off = 1; off < 1024; off <<= 1) {
        int v = (t >= off) ? part[t - off] : 0;
        __syncthreads();
        part[t] += v;
        __syncthreads();
    }
    int run = (t == 0) ? 0 : part[t - 1];
    for (int i = 0; i < CHUNK; ++i) {
        int idx = base + i;
        if (idx < NN) {
            rowptr[idx] = run;
            run += degi[idx];
        }
    }
    if (t == 1023) rowptr[NN] = run;
}

// ---------------------------------------------------------------------------
// Scatter src indices into CSR slots (dst-sorted edge list).
// ---------------------------------------------------------------------------
__global__ __launch_bounds__(256) void scatter_kernel(const void* __restrict__ ei,
                                                      const int* __restrict__ flag,
                                                      const int* __restrict__ rowptr,
                                                      int* __restrict__ cursor,
                                                      int* __restrict__ csr) {
    int e = blockIdx.x * 256 + threadIdx.x;
    if (e >= NE) return;
    int is64 = *flag;
    int s = load_idx(ei, is64, e);
    int d = load_idx(ei, is64, NE + e);
    int pos = rowptr[d] + atomicAdd(&cursor[d], 1);
    csr[pos] = s;
}

// ---------------------------------------------------------------------------
// One-shot prep: transpose the three W matrices into wt layout
//   wt[layer][(k*64 + l)*4 + m] = W_layer[(m*64 + l)*64 + k]
// plus pack U0 into u0pack[k*4+m] = U0[m*64+k], and zero cst0[256].
// ---------------------------------------------------------------------------
__global__ __launch_bounds__(256) void transpose_kernel(const float* __restrict__ W0,
                                                        const float* __restrict__ W1,
                                                        const float* __restrict__ W2,
                                                        const float* __restrict__ U0,
                                                        float* __restrict__ wt,
                                                        float* __restrict__ u0pack,
                                                        float* __restrict__ cst0) {
    int t = blockIdx.x * 256 + threadIdx.x;
    if (t < 3 * 16384) {
        int layer = t / 16384;
        int r = t & 16383;
        int m = r & 3;
        int l = (r >> 2) & 63;
        int k = r >> 8;
        const float* W = (layer == 0) ? W0 : (layer == 1) ? W1 : W2;
        wt[t] = W[(m * 64 + l) * 64 + k];
    } else if (t < 3 * 16384 + 256) {
        int i = t - 3 * 16384;
        int k = i >> 2;
        int m = i & 3;
        u0pack[i] = U0[m * 64 + k];
    } else if (t < 3 * 16384 + 512) {
        cst0[t - 3 * 16384 - 256] = 0.0f;
    }
}

// ---------------------------------------------------------------------------
// BN fold: from stats (sum/sumsq of this layer's post-ReLU h) and the NEXT
// layer's weights, produce scaled weights so BN never materializes:
//   sc[k] = g[k] * rsqrt(var+eps);  sh[k] = bt[k] - mu[k]*sc[k]
//   wsc   = wt_next * sc[k]                (16384)
//   cst[o2] = sum_k sh[k] * Wnext[o2*64+k] (256)   [y constant term]
//   usc[k*4+m] = Unext[m*64+k] * sc[k]     (256)   [p shift cancels in diffs]
// ---------------------------------------------------------------------------
__device__ __forceinline__ float fold_sc(const float* stats, const float* g, int k) {
    const float invN = 1.0f / (float)NN;
    float mu = stats[k] * invN;
    float var = stats[64 + k] * invN - mu * mu;
    return rsqrtf(var + BN_EPS) * g[k];
}

__global__ __launch_bounds__(256) void fold_kernel(const float* __restrict__ stats,
                                                   const float* __restrict__ g,
                                                   const float* __restrict__ bt,
                                                   const float* __restrict__ Wnext,
                                                   const float* __restrict__ Unext,
                                                   const float* __restrict__ wt_next,
                                                   float* __restrict__ wsc,
                                                   float* __restrict__ usc,
                                                   float* __restrict__ cst) {
    int t = blockIdx.x * 256 + threadIdx.x;
    const float invN = 1.0f / (float)NN;
    if (t < 16384) {
        int k = t >> 8;
        wsc[t] = wt_next[t] * fold_sc(stats, g, k);
    } else if (t < 16384 + 256) {
        int o2 = t - 16384;
        float s = 0.0f;
        for (int k = 0; k < 64; ++k) {
            float mu = stats[k] * invN;
            float sc = fold_sc(stats, g, k);
            float sh = bt[k] - mu * sc;
            s += sh * Wnext[o2 * 64 + k];
        }
        cst[o2] = s;
    } else if (t < 16384 + 512) {
        int i = t - 16384 - 256;
        int k = i >> 2;
        int m = i & 3;
        usc[i] = Unext[m * 64 + k] * fold_sc(stats, g, k);
    }
}

// ---------------------------------------------------------------------------
// Fused node transform: from (possibly BN-folded) weights
//   y2[n][o] = bf16x4 of h@wscT (+cst),  p[n][m] = h@uscT
// One wave per 4 nodes; lane = channel o.
// ---------------------------------------------------------------------------
__global__ __launch_bounds__(256) void transform_kernel(const float* __restrict__ h,
                                                        const float4* __restrict__ wt4,
                                                        const float4* __restrict__ usc4,
                                                        const float* __restrict__ cst,
                                                        ushort4* __restrict__ y2,
                                                        float4* __restrict__ pout) {
    int wave = (blockIdx.x * 256 + threadIdx.x) >> 6;  // 0..7499 (exact)
    int lane = threadIdx.x & 63;
    int n0 = wave * 4;
    const float4* h4 = reinterpret_cast<const float4*>(h);

    float acc[4][4];
    float pp[4][4];
#pragma unroll
    for (int j = 0; j < 4; ++j)
#pragma unroll
        for (int m = 0; m < 4; ++m) { acc[j][m] = 0.0f; pp[j][m] = 0.0f; }

#pragma unroll 4
    for (int kb = 0; kb < 16; ++kb) {
        float hb[4][4];
#pragma unroll
        for (int j = 0; j < 4; ++j) {
            float4 v = h4[(size_t)(n0 + j) * 16 + kb];
            hb[j][0] = v.x; hb[j][1] = v.y; hb[j][2] = v.z; hb[j][3] = v.w;
        }
#pragma unroll
        for (int kk = 0; kk < 4; ++kk) {
            float4 wv = wt4[(size_t)(kb * 4 + kk) * 64 + lane];
            float4 uv = usc4[kb * 4 + kk];
#pragma unroll
            for (int j = 0; j < 4; ++j) {
                acc[j][0] += hb[j][kk] * wv.x;
                acc[j][1] += hb[j][kk] * wv.y;
                acc[j][2] += hb[j][kk] * wv.z;
                acc[j][3] += hb[j][kk] * wv.w;
                pp[j][0] += hb[j][kk] * uv.x;
                pp[j][1] += hb[j][kk] * uv.y;
                pp[j][2] += hb[j][kk] * uv.z;
                pp[j][3] += hb[j][kk] * uv.w;
            }
        }
    }
    float c0 = cst[lane];
    float c1 = cst[64 + lane];
    float c2 = cst[128 + lane];
    float c3 = cst[192 + lane];
#pragma unroll
    for (int j = 0; j < 4; ++j) {
        ushort4 o;
        o.x = f2bf(acc[j][0] + c0);
        o.y = f2bf(acc[j][1] + c1);
        o.z = f2bf(acc[j][2] + c2);
        o.w = f2bf(acc[j][3] + c3);
        y2[(size_t)(n0 + j) * 64 + lane] = o;
    }
    // p store: all lanes hold identical pp; lanes 0..3 each store one node
    if (lane < 4) {
        float4 v = make_float4(pp[0][0], pp[0][1], pp[0][2], pp[0][3]);
        if (lane == 1) v = make_float4(pp[1][0], pp[1][1], pp[1][2], pp[1][3]);
        if (lane == 2) v = make_float4(pp[2][0], pp[2][1], pp[2][2], pp[2][3]);
        if (lane == 3) v = make_float4(pp[3][0], pp[3][1], pp[3][2], pp[3][3]);
        pout[n0 + lane] = v;
    }
}

// ---------------------------------------------------------------------------
// Fused aggregate: one wave per dst node, lane = output channel.
// Phase 1 (per 64-edge chunk): each lane computes ONE edge's normalized
// attention (softmax w/ max-sub — REQUIRED, see R5 NaN) into LDS.
// Phase 2: per edge, broadcast attn + src from LDS, gather y2, 4 FMAs.
// Wave-synchronous LDS (single wave owns its slots; DS ops in-order per wave).
// ---------------------------------------------------------------------------
template <int DO_RELU_STATS>
__global__ __launch_bounds__(256) void aggregate_kernel(const int* __restrict__ rowptr,
                                                        const int* __restrict__ csr,
                                                        const float* __restrict__ p,
                                                        const ushort4* __restrict__ y2,
                                                        const float* __restrict__ cvec,
                                                        const float* __restrict__ bvec,
                                                        float* __restrict__ hout,
                                                        float* __restrict__ partial) {
    __shared__ float4 attn_s[4][64];
    __shared__ int src_s[4][64];
    int wid = threadIdx.x >> 6;
    int lane = threadIdx.x & 63;
    int n = blockIdx.x * 4 + wid;
    const float4* p4 = reinterpret_cast<const float4*>(p);

    float4 cv = make_float4(cvec[0], cvec[1], cvec[2], cvec[3]);
    float4 pd = p4[n];
    float4 pdc = make_float4(pd.x + cv.x, pd.y + cv.y, pd.z + cv.z, pd.w + cv.w);

    // self-loop attention = softmax(c), node-independent
    float smx = fmaxf(fmaxf(cv.x, cv.y), fmaxf(cv.z, cv.w));
    float se0 = __expf(cv.x - smx), se1 = __expf(cv.y - smx);
    float se2 = __expf(cv.z - smx), se3 = __expf(cv.w - smx);
    float sinv = 1.0f / (se0 + se1 + se2 + se3);
    ushort4 ws = y2[(unsigned)(n * 64 + lane)];
    float acc0 = (se0 * bf2f(ws.x) + se1 * bf2f(ws.y) +
                  se2 * bf2f(ws.z) + se3 * bf2f(ws.w)) * sinv;
    float acc1 = 0.0f;

    int start = rowptr[n];
    int end = rowptr[n + 1];
    for (int j = start; j < end; j += 64) {
        int chunk = end - j;
        if (chunk > 64) chunk = 64;
        if (lane < chunk) {
            int s = csr[j + lane];
            float4 q = p4[(unsigned)s];
            float l0 = pdc.x - q.x;
            float l1 = pdc.y - q.y;
            float l2 = pdc.z - q.z;
            float l3 = pdc.w - q.w;
            float mx = fmaxf(fmaxf(l0, l1), fmaxf(l2, l3));
            float e0 = __expf(l0 - mx);
            float e1 = __expf(l1 - mx);
            float e2 = __expf(l2 - mx);
            float e3 = __expf(l3 - mx);
            float inv = 1.0f / (e0 + e1 + e2 + e3);
            attn_s[wid][lane] = make_float4(e0 * inv, e1 * inv, e2 * inv, e3 * inv);
            src_s[wid][lane] = s;
        }
        int k = 0;
        for (; k + 2 <= chunk; k += 2) {
            float4 a0 = attn_s[wid][k];
            int s0 = src_s[wid][k];
            float4 a1 = attn_s[wid][k + 1];
            int s1 = src_s[wid][k + 1];
            ushort4 w0 = y2[(unsigned)(s0 * 64 + lane)];
            ushort4 w1 = y2[(unsigned)(s1 * 64 + lane)];
            acc0 += a0.x * bf2f(w0.x) + a0.y * bf2f(w0.y) +
                    a0.z * bf2f(w0.z) + a0.w * bf2f(w0.w);
            acc1 += a1.x * bf2f(w1.x) + a1.y * bf2f(w1.y) +
                    a1.z * bf2f(w1.z) + a1.w * bf2f(w1.w);
        }
        if (k < chunk) {
            float4 a0 = attn_s[wid][k];
            int s0 = src_s[wid][k];
            ushort4 w0 = y2[(unsigned)(s0 * 64 + lane)];
            acc0 += a0.x * bf2f(w0.x) + a0.y * bf2f(w0.y) +
                    a0.z * bf2f(w0.z) + a0.w * bf2f(w0.w);
        }
    }

    float val = (acc0 + acc1) / (float)(end - start + 1) + bvec[lane];

    if (DO_RELU_STATS) {
        val = fmaxf(val, 0.0f);
        hout[(size_t)n * 64 + lane] = val;
        __shared__ float s1m[256];
        __shared__ float s2m[256];
        s1m[threadIdx.x] = val;
        s2m[threadIdx.x] = val * val;
        __syncthreads();
        if (threadIdx.x < 64) {
            float s = s1m[threadIdx.x] + s1m[threadIdx.x + 64] +
                      s1m[threadIdx.x + 128] + s1m[threadIdx.x + 192];
            float q = s2m[threadIdx.x] + s2m[threadIdx.x + 64] +
                      s2m[threadIdx.x + 128] + s2m[threadIdx.x + 192];
            partial[blockIdx.x * 128 + threadIdx.x] = s;
            partial[blockIdx.x * 128 + 64 + threadIdx.x] = q;
        }
    } else {
        hout[(size_t)n * 64 + lane] = val;
    }
}

// ---------------------------------------------------------------------------
// Reduce per-block partials -> stats[128]. One block per slot.
// ---------------------------------------------------------------------------
__global__ __launch_bounds__(256) void reduce_kernel(const float* __restrict__ partial,
                                                     float* __restrict__ stats) {
    int slot = blockIdx.x;           // 0..127
    float acc = 0.0f;
    for (int j = threadIdx.x; j < NBLK; j += 256)
        acc += partial[(size_t)j * 128 + slot];
    __shared__ float sm[256];
    sm[threadIdx.x] = acc;
    __syncthreads();
    for (int off = 128; off > 0; off >>= 1) {
        if (threadIdx.x < off) sm[threadIdx.x] += sm[threadIdx.x + off];
        __syncthreads();
    }
    if (threadIdx.x == 0) stats[slot] = sm[0];
}

extern "C" void kernel_launch(void* const* d_in, const int* in_sizes, int n_in,
                              void* d_out, int out_size, void* d_ws, size_t ws_size,
                              hipStream_t stream) {
    const float* x = (const float*)d_in[0];
    const void* ei = d_in[1];
    const float* W0 = (const float*)d_in[2];
    const float* U0 = (const float*)d_in[3];
    const float* c0 = (const float*)d_in[4];
    const float* b0 = (const float*)d_in[5];
    const float* g0 = (const float*)d_in[6];
    const float* bt0 = (const float*)d_in[7];
    const float* W1 = (const float*)d_in[8];
    const float* U1 = (const float*)d_in[9];
    const float* c1 = (const float*)d_in[10];
    const float* b1 = (const float*)d_in[11];
    const float* g1 = (const float*)d_in[12];
    const float* bt1 = (const float*)d_in[13];
    const float* W2 = (const float*)d_in[14];
    const float* U2 = (const float*)d_in[15];
    const float* c2 = (const float*)d_in[16];
    const float* b2 = (const float*)d_in[17];

    float* ws = (float*)d_ws;
    float* wt = ws;                          // 3*16384
    float* wsc = wt + 3 * 16384;             // 16384
    float* usc = wsc + 16384;                // 256
    float* cst = usc + 256;                  // 256
    float* u0pack = cst + 256;               // 256
    float* cst0 = u0pack + 256;              // 256
    ushort4* y2 = (ushort4*)(cst0 + 256);    // NN*64 ushort4 (15.36 MB)
    float* p = (float*)((unsigned short*)y2 + (size_t)NN * 256);  // NN*4
    float* h1 = p + (size_t)NN * 4;          // NN*64
    float* h2 = h1 + (size_t)NN * 64;        // NN*64
    float* stats = h2 + (size_t)NN * 64;     // 128
    float* partial = stats + 128;            // NBLK*128
    int* degi = (int*)(partial + (size_t)NBLK * 128);  // NN
    int* cursor = degi + NN;                 // NN  (contiguous w/ degi: 1 memset)
    int* rowptr = cursor + NN;               // NN+1
    int* csr = rowptr + NN + 1;              // NE
    int* flag = csr + NE;                    // 1

    const int TB = 256;
    const int tfBlocks = (NN / 4) * 64 / TB;         // 1875 exact
    const int aggBlocks = NBLK;                      // 7500 (wave per node)
    const int eBlocks = NE / TB;                     // 1875 exact
    const int trBlocks = (3 * 16384 + 512 + TB - 1) / TB;  // 194
    const int foldBlocks = (16384 + 512 + TB - 1) / TB;    // 66

    // ---- one-shot prep: dtype flag, weight repack, CSR by dst ----
    detect_kernel<<<1, 64, 0, stream>>>((const unsigned int*)ei, flag);
    transpose_kernel<<<trBlocks, TB, 0, stream>>>(W0, W1, W2, U0, wt, u0pack, cst0);
    hipMemsetAsync(degi, 0, sizeof(int) * 2 * NN, stream);
    hist_kernel<<<eBlocks, TB, 0, stream>>>(ei, flag, degi);
    scan_kernel<<<1, 1024, 0, stream>>>(degi, rowptr);
    scatter_kernel<<<eBlocks, TB, 0, stream>>>(ei, flag, rowptr, cursor, csr);

    const float4* wt4_0 = reinterpret_cast<const float4*>(wt);
    const float4* wsc4 = reinterpret_cast<const float4*>(wsc);
    const float4* usc4 = reinterpret_cast<const float4*>(usc);
    const float4* u0pack4 = reinterpret_cast<const float4*>(u0pack);
    float4* p4 = reinterpret_cast<float4*>(p);

    // ---- layer 0 (no BN in front: raw W0/U0, zero cst) ----
    transform_kernel<<<tfBlocks, TB, 0, stream>>>(x, wt4_0, u0pack4, cst0, y2, p4);
    aggregate_kernel<1><<<aggBlocks, TB, 0, stream>>>(rowptr, csr, p, y2, c0, b0, h1, partial);
    reduce_kernel<<<128, TB, 0, stream>>>(partial, stats);
    fold_kernel<<<foldBlocks, TB, 0, stream>>>(stats, g0, bt0, W1, U1, wt + 16384, wsc, usc, cst);

    // ---- layer 1 (BN0 folded into W1/U1) ----
    transform_kernel<<<tfBlocks, TB, 0, stream>>>(h1, wsc4, usc4, cst, y2, p4);
    aggregate_kernel<1><<<aggBlocks, TB, 0, stream>>>(rowptr, csr, p, y2, c1, b1, h2, partial);
    reduce_kernel<<<128, TB, 0, stream>>>(partial, stats);
    fold_kernel<<<foldBlocks, TB, 0, stream>>>(stats, g1, bt1, W2, U2, wt + 2 * 16384, wsc, usc, cst);

    // ---- layer 2 (BN1 folded into W2/U2) ----
    transform_kernel<<<tfBlocks, TB, 0, stream>>>(h2, wsc4, usc4, cst, y2, p4);
    aggregate_kernel<0><<<aggBlocks, TB, 0, stream>>>(rowptr, csr, p, y2, c2, b2, (float*)d_out, nullptr);
}

// Round 9
// 410.243 us; speedup vs baseline: 3.5949x; 1.0802x over previous
//
#include <hip/hip_runtime.h>

#define NN 30000
#define NE 480000
#define CH 64
#define NH 4
#define BN_EPS 1e-5f
#define NBLK 7500   // NN/4 aggregate blocks (256 thr = 4 waves = 4 nodes)
#define SCB 118     // ceil(NN/256) scan blocks

// ---------------------------------------------------------------------------
// bf16 helpers (RNE pack, cheap unpack)
// ---------------------------------------------------------------------------
__device__ __forceinline__ unsigned short f2bf(float x) {
    unsigned int u = __float_as_uint(x);
    return (unsigned short)((u + 0x7fffu + ((u >> 16) & 1u)) >> 16);
}
__device__ __forceinline__ float bf2f(unsigned short h) {
    return __uint_as_float(((unsigned int)h) << 16);
}

// ---------------------------------------------------------------------------
// Detect int64 vs int32 edge_index (all odd 32-bit words zero => int64).
// Serial known-good version (R7).
// ---------------------------------------------------------------------------
__global__ __launch_bounds__(64) void detect_kernel(const unsigned int* __restrict__ ei,
                                                    int* __restrict__ flag) {
    if (threadIdx.x == 0 && blockIdx.x == 0) {
        int all0 = 1;
        for (int i = 0; i < 64; ++i) {
            if (ei[2 * i + 1] != 0u) all0 = 0;
        }
        *flag = all0;
    }
}

__device__ __forceinline__ int load_idx(const void* ei, int is64, int pos) {
    if (is64) return (int)((const long long*)ei)[pos];
    return ((const int*)ei)[pos];
}

// ---------------------------------------------------------------------------
// Histogram of dst degrees (real edges only).
// ---------------------------------------------------------------------------
__global__ __launch_bounds__(256) void hist_kernel(const void* __restrict__ ei,
                                                   const int* __restrict__ flag,
                                                   int* __restrict__ degi) {
    int e = blockIdx.x * 256 + threadIdx.x;
    if (e >= NE) return;
    int is64 = *flag;
    int d = load_idx(ei, is64, NE + e);
    atomicAdd(&degi[d], 1);
}

// ---------------------------------------------------------------------------
// Scan phase A: per-block sums of degi -> bsum[SCB].
// ---------------------------------------------------------------------------
__global__ __launch_bounds__(256) void scanA_kernel(const int* __restrict__ degi,
                                                    int* __restrict__ bsum) {
    int t = blockIdx.x * 256 + threadIdx.x;
    int v = (t < NN) ? degi[t] : 0;
    __shared__ int sm[256];
    sm[threadIdx.x] = v;
    __syncthreads();
    for (int off = 128; off > 0; off >>= 1) {
        if (threadIdx.x < off) sm[threadIdx.x] += sm[threadIdx.x + off];
        __syncthreads();
    }
    if (threadIdx.x == 0) bsum[blockIdx.x] = sm[0];
}

// ---------------------------------------------------------------------------
// Scan phase B: one 128-thread block, exclusive scan of bsum -> boff.
// ---------------------------------------------------------------------------
__global__ __launch_bounds__(128) void scanB_kernel(const int* __restrict__ bsum,
                                                    int* __restrict__ boff) {
    __shared__ int sm[128];
    int t = threadIdx.x;
    int v = (t < SCB) ? bsum[t] : 0;
    sm[t] = v;
    __syncthreads();
    for (int off = 1; off < 128; off <<= 1) {
        int add = (t >= off) ? sm[t - off] : 0;
        __syncthreads();
        sm[t] += add;
        __syncthreads();
    }
    if (t < SCB) boff[t] = sm[t] - v;  // exclusive
}

// ---------------------------------------------------------------------------
// Scan phase C: rowptr[t] = boff[block] + exclusive-in-block scan of degi.
// ---------------------------------------------------------------------------
__global__ __launch_bounds__(256) void scanC_kernel(const int* __restrict__ degi,
                                                    const int* __restrict__ boff,
                                                    int* __restrict__ rowptr) {
    __shared__ int sm[256];
    int b = blockIdx.x;
    int t = b * 256 + threadIdx.x;
    int d = (t < NN) ? degi[t] : 0;
    sm[threadIdx.x] = d;
    __syncthreads();
    for (int off = 1; off < 256; off <<= 1) {
        int add = (threadIdx.x >= off) ? sm[threadIdx.x - off] : 0;
        __syncthreads();
        sm[threadIdx.x] += add;
        __syncthreads();
    }
    if (t < NN) rowptr[t] = boff[b] + sm[threadIdx.x] - d;  // exclusive
    if (b == 0 && threadIdx.x == 0) rowptr[NN] = NE;
}

// ---------------------------------------------------------------------------
// Scatter src indices into CSR slots (dst-sorted edge list).
// ---------------------------------------------------------------------------
__global__ __launch_bounds__(256) void scatter_kernel(const void* __restrict__ ei,
                                                      const int* __restrict__ flag,
                                                      const int* __restrict__ rowptr,
                                                      int* __restrict__ cursor,
                                                      int* __restrict__ csr) {
    int e = blockIdx.x * 256 + threadIdx.x;
    if (e >= NE) return;
    int is64 = *flag;
    int s = load_idx(ei, is64, e);
    int d = load_idx(ei, is64, NE + e);
    int pos = rowptr[d] + atomicAdd(&cursor[d], 1);
    csr[pos] = s;
}

// ---------------------------------------------------------------------------
// One-shot prep: transpose the three W matrices into wt layout
//   wt[layer][(k*64 + l)*4 + m] = W_layer[(m*64 + l)*64 + k]
// plus pack U0 into u0pack[k*4+m] = U0[m*64+k], and zero cst0[256].
// ---------------------------------------------------------------------------
__global__ __launch_bounds__(256) void transpose_kernel(const float* __restrict__ W0,
                                                        const float* __restrict__ W1,
                                                        const float* __restrict__ W2,
                                                        const float* __restrict__ U0,
                                                        float* __restrict__ wt,
                                                        float* __restrict__ u0pack,
                                                        float* __restrict__ cst0) {
    int t = blockIdx.x * 256 + threadIdx.x;
    if (t < 3 * 16384) {
        int layer = t / 16384;
        int r = t & 16383;
        int m = r & 3;
        int l = (r >> 2) & 63;
        int k = r >> 8;
        const float* W = (layer == 0) ? W0 : (layer == 1) ? W1 : W2;
        wt[t] = W[(m * 64 + l) * 64 + k];
    } else if (t < 3 * 16384 + 256) {
        int i = t - 3 * 16384;
        int k = i >> 2;
        int m = i & 3;
        u0pack[i] = U0[m * 64 + k];
    } else if (t < 3 * 16384 + 512) {
        cst0[t - 3 * 16384 - 256] = 0.0f;
    }
}

// ---------------------------------------------------------------------------
// BN fold: from stats (sum/sumsq of this layer's post-ReLU h) and the NEXT
// layer's weights, produce scaled weights so BN never materializes:
//   sc[k] = g[k]*rsqrt(var+eps);  sh[k] = bt[k] - mu[k]*sc[k]
//   wsc = wt_next*sc[k]; cst[o2] = sum_k sh[k]*Wnext[o2*64+k];
//   usc[k*4+m] = Unext[m*64+k]*sc[k]  (p shift cancels in logit differences)
// ---------------------------------------------------------------------------
__device__ __forceinline__ float fold_sc(const float* stats, const float* g, int k) {
    const float invN = 1.0f / (float)NN;
    float mu = stats[k] * invN;
    float var = stats[64 + k] * invN - mu * mu;
    return rsqrtf(var + BN_EPS) * g[k];
}

__global__ __launch_bounds__(256) void fold_kernel(const float* __restrict__ stats,
                                                   const float* __restrict__ g,
                                                   const float* __restrict__ bt,
                                                   const float* __restrict__ Wnext,
                                                   const float* __restrict__ Unext,
                                                   const float* __restrict__ wt_next,
                                                   float* __restrict__ wsc,
                                                   float* __restrict__ usc,
                                                   float* __restrict__ cst) {
    int t = blockIdx.x * 256 + threadIdx.x;
    const float invN = 1.0f / (float)NN;
    if (t < 16384) {
        int k = t >> 8;
        wsc[t] = wt_next[t] * fold_sc(stats, g, k);
    } else if (t < 16384 + 256) {
        int o2 = t - 16384;
        float s = 0.0f;
        for (int k = 0; k < 64; ++k) {
            float mu = stats[k] * invN;
            float sc = fold_sc(stats, g, k);
            float sh = bt[k] - mu * sc;
            s += sh * Wnext[o2 * 64 + k];
        }
        cst[o2] = s;
    } else if (t < 16384 + 512) {
        int i = t - 16384 - 256;
        int k = i >> 2;
        int m = i & 3;
        usc[i] = Unext[m * 64 + k] * fold_sc(stats, g, k);
    }
}

// ---------------------------------------------------------------------------
// Node transform: y2[n][o] = bf16x4 of h@wtT (+cst). Wave per 4 nodes.
// ---------------------------------------------------------------------------
__global__ __launch_bounds__(256) void transform_kernel(const float* __restrict__ h,
                                                        const float4* __restrict__ wt4,
                                                        const float* __restrict__ cst,
                                                        ushort4* __restrict__ y2) {
    int wave = (blockIdx.x * 256 + threadIdx.x) >> 6;  // 0..7499 (exact)
    int lane = threadIdx.x & 63;
    int n0 = wave * 4;
    const float4* h4 = reinterpret_cast<const float4*>(h);

    float acc[4][4];
#pragma unroll
    for (int j = 0; j < 4; ++j)
#pragma unroll
        for (int m = 0; m < 4; ++m) acc[j][m] = 0.0f;

#pragma unroll 4
    for (int kb = 0; kb < 16; ++kb) {
        float hb[4][4];
#pragma unroll
        for (int j = 0; j < 4; ++j) {
            float4 v = h4[(size_t)(n0 + j) * 16 + kb];
            hb[j][0] = v.x; hb[j][1] = v.y; hb[j][2] = v.z; hb[j][3] = v.w;
        }
#pragma unroll
        for (int kk = 0; kk < 4; ++kk) {
            float4 wv = wt4[(size_t)(kb * 4 + kk) * 64 + lane];
#pragma unroll
            for (int j = 0; j < 4; ++j) {
                acc[j][0] += hb[j][kk] * wv.x;
                acc[j][1] += hb[j][kk] * wv.y;
                acc[j][2] += hb[j][kk] * wv.z;
                acc[j][3] += hb[j][kk] * wv.w;
            }
        }
    }
    float c0 = cst[lane];
    float c1 = cst[64 + lane];
    float c2 = cst[128 + lane];
    float c3 = cst[192 + lane];
#pragma unroll
    for (int j = 0; j < 4; ++j) {
        ushort4 o;
        o.x = f2bf(acc[j][0] + c0);
        o.y = f2bf(acc[j][1] + c1);
        o.z = f2bf(acc[j][2] + c2);
        o.w = f2bf(acc[j][3] + c3);
        y2[(size_t)(n0 + j) * 64 + lane] = o;
    }
}

// ---------------------------------------------------------------------------
// p[n][0..3] = h[n,:] @ usc  (usc[k*4+m], BN-folded). Thread per node.
// ---------------------------------------------------------------------------
__global__ __launch_bounds__(256) void p_kernel(const float* __restrict__ h,
                                                const float4* __restrict__ usc4,
                                                float4* __restrict__ pout) {
    int n = blockIdx.x * 256 + threadIdx.x;
    if (n >= NN) return;
    const float4* h4 = reinterpret_cast<const float4*>(h) + (size_t)n * 16;
    float4 acc = make_float4(0.f, 0.f, 0.f, 0.f);
#pragma unroll
    for (int j = 0; j < 16; ++j) {
        float4 hv = h4[j];
        float4 u0 = usc4[4 * j + 0];
        float4 u1 = usc4[4 * j + 1];
        float4 u2 = usc4[4 * j + 2];
        float4 u3 = usc4[4 * j + 3];
        acc.x += hv.x * u0.x + hv.y * u1.x + hv.z * u2.x + hv.w * u3.x;
        acc.y += hv.x * u0.y + hv.y * u1.y + hv.z * u2.y + hv.w * u3.y;
        acc.z += hv.x * u0.z + hv.y * u1.z + hv.z * u2.z + hv.w * u3.z;
        acc.w += hv.x * u0.w + hv.y * u1.w + hv.z * u2.w + hv.w * u3.w;
    }
    pout[n] = acc;
}

// ---------------------------------------------------------------------------
// Fused aggregate: one wave per dst node, lane = output channel.
// Phase 1 (per 64-edge chunk): each lane computes ONE edge's normalized
// attention (softmax w/ max-sub — REQUIRED, see R5 NaN) into LDS.
// Phase 2: per edge, broadcast attn + src from LDS, gather y2, 4 FMAs.
// Wave-synchronous LDS (single wave owns its slots; DS ops in-order per wave).
// ---------------------------------------------------------------------------
template <int DO_RELU_STATS>
__global__ __launch_bounds__(256) void aggregate_kernel(const int* __restrict__ rowptr,
                                                        const int* __restrict__ csr,
                                                        const float* __restrict__ p,
                                                        const ushort4* __restrict__ y2,
                                                        const float* __restrict__ cvec,
                                                        const float* __restrict__ bvec,
                                                        float* __restrict__ hout,
                                                        float* __restrict__ partial) {
    __shared__ float4 attn_s[4][64];
    __shared__ int src_s[4][64];
    int wid = threadIdx.x >> 6;
    int lane = threadIdx.x & 63;
    int n = blockIdx.x * 4 + wid;
    const float4* p4 = reinterpret_cast<const float4*>(p);

    float4 cv = make_float4(cvec[0], cvec[1], cvec[2], cvec[3]);
    float4 pd = p4[n];
    float4 pdc = make_float4(pd.x + cv.x, pd.y + cv.y, pd.z + cv.z, pd.w + cv.w);

    // self-loop attention = softmax(c), node-independent
    float smx = fmaxf(fmaxf(cv.x, cv.y), fmaxf(cv.z, cv.w));
    float se0 = __expf(cv.x - smx), se1 = __expf(cv.y - smx);
    float se2 = __expf(cv.z - smx), se3 = __expf(cv.w - smx);
    float sinv = 1.0f / (se0 + se1 + se2 + se3);
    ushort4 ws = y2[(unsigned)(n * 64 + lane)];
    float acc0 = (se0 * bf2f(ws.x) + se1 * bf2f(ws.y) +
                  se2 * bf2f(ws.z) + se3 * bf2f(ws.w)) * sinv;
    float acc1 = 0.0f;

    int start = rowptr[n];
    int end = rowptr[n + 1];
    for (int j = start; j < end; j += 64) {
        int chunk = end - j;
        if (chunk > 64) chunk = 64;
        if (lane < chunk) {
            int s = csr[j + lane];
            float4 q = p4[(unsigned)s];
            float l0 = pdc.x - q.x;
            float l1 = pdc.y - q.y;
            float l2 = pdc.z - q.z;
            float l3 = pdc.w - q.w;
            float mx = fmaxf(fmaxf(l0, l1), fmaxf(l2, l3));
            float e0 = __expf(l0 - mx);
            float e1 = __expf(l1 - mx);
            float e2 = __expf(l2 - mx);
            float e3 = __expf(l3 - mx);
            float inv = 1.0f / (e0 + e1 + e2 + e3);
            attn_s[wid][lane] = make_float4(e0 * inv, e1 * inv, e2 * inv, e3 * inv);
            src_s[wid][lane] = s;
        }
        int k = 0;
        for (; k + 2 <= chunk; k += 2) {
            float4 a0 = attn_s[wid][k];
            int s0 = src_s[wid][k];
            float4 a1 = attn_s[wid][k + 1];
            int s1 = src_s[wid][k + 1];
            ushort4 w0 = y2[(unsigned)(s0 * 64 + lane)];
            ushort4 w1 = y2[(unsigned)(s1 * 64 + lane)];
            acc0 += a0.x * bf2f(w0.x) + a0.y * bf2f(w0.y) +
                    a0.z * bf2f(w0.z) + a0.w * bf2f(w0.w);
            acc1 += a1.x * bf2f(w1.x) + a1.y * bf2f(w1.y) +
                    a1.z * bf2f(w1.z) + a1.w * bf2f(w1.w);
        }
        if (k < chunk) {
            float4 a0 = attn_s[wid][k];
            int s0 = src_s[wid][k];
            ushort4 w0 = y2[(unsigned)(s0 * 64 + lane)];
            acc0 += a0.x * bf2f(w0.x) + a0.y * bf2f(w0.y) +
                    a0.z * bf2f(w0.z) + a0.w * bf2f(w0.w);
        }
    }

    float val = (acc0 + acc1) / (float)(end - start + 1) + bvec[lane];

    if (DO_RELU_STATS) {
        val = fmaxf(val, 0.0f);
        hout[(size_t)n * 64 + lane] = val;
        __shared__ float s1m[256];
        __shared__ float s2m[256];
        s1m[threadIdx.x] = val;
        s2m[threadIdx.x] = val * val;
        __syncthreads();
        if (threadIdx.x < 64) {
            float s = s1m[threadIdx.x] + s1m[threadIdx.x + 64] +
                      s1m[threadIdx.x + 128] + s1m[threadIdx.x + 192];
            float q = s2m[threadIdx.x] + s2m[threadIdx.x + 64] +
                      s2m[threadIdx.x + 128] + s2m[threadIdx.x + 192];
            partial[blockIdx.x * 128 + threadIdx.x] = s;
            partial[blockIdx.x * 128 + 64 + threadIdx.x] = q;
        }
    } else {
        hout[(size_t)n * 64 + lane] = val;
    }
}

// ---------------------------------------------------------------------------
// Reduce per-block partials -> stats[128]. One block per slot.
// ---------------------------------------------------------------------------
__global__ __launch_bounds__(256) void reduce_kernel(const float* __restrict__ partial,
                                                     float* __restrict__ stats) {
    int slot = blockIdx.x;           // 0..127
    float acc = 0.0f;
    for (int j = threadIdx.x; j < NBLK; j += 256)
        acc += partial[(size_t)j * 128 + slot];
    __shared__ float sm[256];
    sm[threadIdx.x] = acc;
    __syncthreads();
    for (int off = 128; off > 0; off >>= 1) {
        if (threadIdx.x < off) sm[threadIdx.x] += sm[threadIdx.x + off];
        __syncthreads();
    }
    if (threadIdx.x == 0) stats[slot] = sm[0];
}

extern "C" void kernel_launch(void* const* d_in, const int* in_sizes, int n_in,
                              void* d_out, int out_size, void* d_ws, size_t ws_size,
                              hipStream_t stream) {
    const float* x = (const float*)d_in[0];
    const void* ei = d_in[1];
    const float* W0 = (const float*)d_in[2];
    const float* U0 = (const float*)d_in[3];
    const float* c0 = (const float*)d_in[4];
    const float* b0 = (const float*)d_in[5];
    const float* g0 = (const float*)d_in[6];
    const float* bt0 = (const float*)d_in[7];
    const float* W1 = (const float*)d_in[8];
    const float* U1 = (const float*)d_in[9];
    const float* c1 = (const float*)d_in[10];
    const float* b1 = (const float*)d_in[11];
    const float* g1 = (const float*)d_in[12];
    const float* bt1 = (const float*)d_in[13];
    const float* W2 = (const float*)d_in[14];
    const float* U2 = (const float*)d_in[15];
    const float* c2 = (const float*)d_in[16];
    const float* b2 = (const float*)d_in[17];

    float* ws = (float*)d_ws;
    float* wt = ws;                          // 3*16384
    float* wsc = wt + 3 * 16384;             // 16384
    float* usc = wsc + 16384;                // 256
    float* cst = usc + 256;                  // 256
    float* u0pack = cst + 256;               // 256
    float* cst0 = u0pack + 256;              // 256
    ushort4* y2 = (ushort4*)(cst0 + 256);    // NN*64 ushort4 (15.36 MB)
    float* p = (float*)((unsigned short*)y2 + (size_t)NN * 256);  // NN*4
    float* h1 = p + (size_t)NN * 4;          // NN*64
    float* h2 = h1 + (size_t)NN * 64;        // NN*64
    float* stats = h2 + (size_t)NN * 64;     // 128
    float* partial = stats + 128;            // NBLK*128
    int* degi = (int*)(partial + (size_t)NBLK * 128);  // NN
    int* cursor = degi + NN;                 // NN  (contiguous w/ degi: 1 memset)
    int* rowptr = cursor + NN;               // NN+1
    int* csr = rowptr + NN + 1;              // NE
    int* bsum = csr + NE;                    // SCB
    int* boff = bsum + SCB;                  // SCB
    int* flag = boff + SCB;                  // 1

    const int TB = 256;
    const int tfBlocks = (NN / 4) * 64 / TB;         // 1875 exact
    const int aggBlocks = NBLK;                      // 7500 (wave per node)
    const int eBlocks = NE / TB;                     // 1875 exact
    const int nBlocks = (NN + TB - 1) / TB;          // 118
    const int trBlocks = (3 * 16384 + 512 + TB - 1) / TB;  // 194
    const int foldBlocks = (16384 + 512 + TB - 1) / TB;    // 66

    // ---- one-shot prep: dtype flag, weight repack, CSR by dst ----
    detect_kernel<<<1, 64, 0, stream>>>((const unsigned int*)ei, flag);
    transpose_kernel<<<trBlocks, TB, 0, stream>>>(W0, W1, W2, U0, wt, u0pack, cst0);
    hipMemsetAsync(degi, 0, sizeof(int) * 2 * NN, stream);
    hist_kernel<<<eBlocks, TB, 0, stream>>>(ei, flag, degi);
    scanA_kernel<<<SCB, TB, 0, stream>>>(degi, bsum);
    scanB_kernel<<<1, 128, 0, stream>>>(bsum, boff);
    scanC_kernel<<<SCB, TB, 0, stream>>>(degi, boff, rowptr);
    scatter_kernel<<<eBlocks, TB, 0, stream>>>(ei, flag, rowptr, cursor, csr);

    const float4* wt4_0 = reinterpret_cast<const float4*>(wt);
    const float4* wsc4 = reinterpret_cast<const float4*>(wsc);
    const float4* usc4 = reinterpret_cast<const float4*>(usc);
    const float4* u0pack4 = reinterpret_cast<const float4*>(u0pack);
    float4* p4 = reinterpret_cast<float4*>(p);

    // ---- layer 0 (no BN in front: raw W0/U0, zero cst) ----
    transform_kernel<<<tfBlocks, TB, 0, stream>>>(x, wt4_0, cst0, y2);
    p_kernel<<<nBlocks, TB, 0, stream>>>(x, u0pack4, p4);
    aggregate_kernel<1><<<aggBlocks, TB, 0, stream>>>(rowptr, csr, p, y2, c0, b0, h1, partial);
    reduce_kernel<<<128, TB, 0, stream>>>(partial, stats);
    fold_kernel<<<foldBlocks, TB, 0, stream>>>(stats, g0, bt0, W1, U1, wt + 16384, wsc, usc, cst);

    // ---- layer 1 (BN0 folded into W1/U1) ----
    transform_kernel<<<tfBlocks, TB, 0, stream>>>(h1, wsc4, cst, y2);
    p_kernel<<<nBlocks, TB, 0, stream>>>(h1, usc4, p4);
    aggregate_kernel<1><<<aggBlocks, TB, 0, stream>>>(rowptr, csr, p, y2, c1, b1, h2, partial);
    reduce_kernel<<<128, TB, 0, stream>>>(partial, stats);
    fold_kernel<<<foldBlocks, TB, 0, stream>>>(stats, g1, bt1, W2, U2, wt + 2 * 16384, wsc, usc, cst);

    // ---- layer 2 (BN1 folded into W2/U2) ----
    transform_kernel<<<tfBlocks, TB, 0, stream>>>(h2, wsc4, cst, y2);
    p_kernel<<<nBlocks, TB, 0, stream>>>(h2, usc4, p4);
    aggregate_kernel<0><<<aggBlocks, TB, 0, stream>>>(rowptr, csr, p, y2, c2, b2, (float*)d_out, nullptr);
}

// Round 10
// 392.893 us; speedup vs baseline: 3.7536x; 1.0442x over previous
//
#include <hip/hip_runtime.h>

#define NN 30000
#define NE 480000
#define CH 64
#define NH 4
#define BN_EPS 1e-5f
#define NBLK 7500   // NN/4 aggregate blocks (256 thr = 4 waves = 4 nodes)
#define SCB 118     // ceil(NN/256) scan blocks

// ---------------------------------------------------------------------------
// bf16 helpers (RNE pack, cheap unpack)
// ---------------------------------------------------------------------------
__device__ __forceinline__ unsigned short f2bf(float x) {
    unsigned int u = __float_as_uint(x);
    return (unsigned short)((u + 0x7fffu + ((u >> 16) & 1u)) >> 16);
}
__device__ __forceinline__ float bf2f(unsigned short h) {
    return __uint_as_float(((unsigned int)h) << 16);
}

// ---------------------------------------------------------------------------
// Inline int64-vs-int32 detect: for int64 data the odd 32-bit words are the
// high halves of values < 2^31 -> all zero. 8 consecutive zero odd words from
// random int32 node indices has probability ~(1/30000)^8 ~ 0.
// Wave-uniform addresses -> broadcast loads, L1-hot after first block.
// ---------------------------------------------------------------------------
__device__ __forceinline__ int detect64(const unsigned int* __restrict__ ei) {
    unsigned int v = ei[1] | ei[3] | ei[5] | ei[7] |
                     ei[9] | ei[11] | ei[13] | ei[15];
    return v == 0u;
}

__device__ __forceinline__ int load_idx(const void* ei, int is64, int pos) {
    if (is64) return (int)((const long long*)ei)[pos];
    return ((const int*)ei)[pos];
}

// ---------------------------------------------------------------------------
// Histogram of dst degrees (real edges only).
// ---------------------------------------------------------------------------
__global__ __launch_bounds__(256) void hist_kernel(const void* __restrict__ ei,
                                                   int* __restrict__ degi) {
    int e = blockIdx.x * 256 + threadIdx.x;
    if (e >= NE) return;
    int is64 = detect64((const unsigned int*)ei);
    int d = load_idx(ei, is64, NE + e);
    atomicAdd(&degi[d], 1);
}

// ---------------------------------------------------------------------------
// Scan phase A: per-block sums of degi -> bsum[SCB].
// ---------------------------------------------------------------------------
__global__ __launch_bounds__(256) void scanA_kernel(const int* __restrict__ degi,
                                                    int* __restrict__ bsum) {
    int t = blockIdx.x * 256 + threadIdx.x;
    int v = (t < NN) ? degi[t] : 0;
    __shared__ int sm[256];
    sm[threadIdx.x] = v;
    __syncthreads();
    for (int off = 128; off > 0; off >>= 1) {
        if (threadIdx.x < off) sm[threadIdx.x] += sm[threadIdx.x + off];
        __syncthreads();
    }
    if (threadIdx.x == 0) bsum[blockIdx.x] = sm[0];
}

// ---------------------------------------------------------------------------
// Scan phase B: one 128-thread block, exclusive scan of bsum -> boff.
// ---------------------------------------------------------------------------
__global__ __launch_bounds__(128) void scanB_kernel(const int* __restrict__ bsum,
                                                    int* __restrict__ boff) {
    __shared__ int sm[128];
    int t = threadIdx.x;
    int v = (t < SCB) ? bsum[t] : 0;
    sm[t] = v;
    __syncthreads();
    for (int off = 1; off < 128; off <<= 1) {
        int add = (t >= off) ? sm[t - off] : 0;
        __syncthreads();
        sm[t] += add;
        __syncthreads();
    }
    if (t < SCB) boff[t] = sm[t] - v;  // exclusive
}

// ---------------------------------------------------------------------------
// Scan phase C: rowptr[t] = boff[block] + exclusive-in-block scan of degi.
// ---------------------------------------------------------------------------
__global__ __launch_bounds__(256) void scanC_kernel(const int* __restrict__ degi,
                                                    const int* __restrict__ boff,
                                                    int* __restrict__ rowptr) {
    __shared__ int sm[256];
    int b = blockIdx.x;
    int t = b * 256 + threadIdx.x;
    int d = (t < NN) ? degi[t] : 0;
    sm[threadIdx.x] = d;
    __syncthreads();
    for (int off = 1; off < 256; off <<= 1) {
        int add = (threadIdx.x >= off) ? sm[threadIdx.x - off] : 0;
        __syncthreads();
        sm[threadIdx.x] += add;
        __syncthreads();
    }
    if (t < NN) rowptr[t] = boff[b] + sm[threadIdx.x] - d;  // exclusive
    if (b == 0 && threadIdx.x == 0) rowptr[NN] = NE;
}

// ---------------------------------------------------------------------------
// Scatter src indices into CSR slots (dst-sorted edge list).
// ---------------------------------------------------------------------------
__global__ __launch_bounds__(256) void scatter_kernel(const void* __restrict__ ei,
                                                      const int* __restrict__ rowptr,
                                                      int* __restrict__ cursor,
                                                      int* __restrict__ csr) {
    int e = blockIdx.x * 256 + threadIdx.x;
    if (e >= NE) return;
    int is64 = detect64((const unsigned int*)ei);
    int s = load_idx(ei, is64, e);
    int d = load_idx(ei, is64, NE + e);
    int pos = rowptr[d] + atomicAdd(&cursor[d], 1);
    csr[pos] = s;
}

// ---------------------------------------------------------------------------
// One-shot prep: transpose the three W matrices into wt layout
//   wt[layer][(k*64 + l)*4 + m] = W_layer[(m*64 + l)*64 + k]
// plus pack U0 into u0pack[k*4+m] = U0[m*64+k], and zero cst0[256].
// ---------------------------------------------------------------------------
__global__ __launch_bounds__(256) void transpose_kernel(const float* __restrict__ W0,
                                                        const float* __restrict__ W1,
                                                        const float* __restrict__ W2,
                                                        const float* __restrict__ U0,
                                                        float* __restrict__ wt,
                                                        float* __restrict__ u0pack,
                                                        float* __restrict__ cst0) {
    int t = blockIdx.x * 256 + threadIdx.x;
    if (t < 3 * 16384) {
        int layer = t / 16384;
        int r = t & 16383;
        int m = r & 3;
        int l = (r >> 2) & 63;
        int k = r >> 8;
        const float* W = (layer == 0) ? W0 : (layer == 1) ? W1 : W2;
        wt[t] = W[(m * 64 + l) * 64 + k];
    } else if (t < 3 * 16384 + 256) {
        int i = t - 3 * 16384;
        int k = i >> 2;
        int m = i & 3;
        u0pack[i] = U0[m * 64 + k];
    } else if (t < 3 * 16384 + 512) {
        cst0[t - 3 * 16384 - 256] = 0.0f;
    }
}

// ---------------------------------------------------------------------------
// BN fold: sc[k] = g[k]*rsqrt(var+eps); sh[k] = bt[k]-mu[k]*sc[k]
//   wsc = wt_next*sc[k]; cst[o2] = sum_k sh[k]*Wnext[o2*64+k];
//   usc[k*4+m] = Unext[m*64+k]*sc[k]  (p shift cancels in logit differences)
// ---------------------------------------------------------------------------
__device__ __forceinline__ float fold_sc(const float* stats, const float* g, int k) {
    const float invN = 1.0f / (float)NN;
    float mu = stats[k] * invN;
    float var = stats[64 + k] * invN - mu * mu;
    return rsqrtf(var + BN_EPS) * g[k];
}

__global__ __launch_bounds__(256) void fold_kernel(const float* __restrict__ stats,
                                                   const float* __restrict__ g,
                                                   const float* __restrict__ bt,
                                                   const float* __restrict__ Wnext,
                                                   const float* __restrict__ Unext,
                                                   const float* __restrict__ wt_next,
                                                   float* __restrict__ wsc,
                                                   float* __restrict__ usc,
                                                   float* __restrict__ cst) {
    int t = blockIdx.x * 256 + threadIdx.x;
    const float invN = 1.0f / (float)NN;
    if (t < 16384) {
        int k = t >> 8;
        wsc[t] = wt_next[t] * fold_sc(stats, g, k);
    } else if (t < 16384 + 256) {
        int o2 = t - 16384;
        float s = 0.0f;
        for (int k = 0; k < 64; ++k) {
            float mu = stats[k] * invN;
            float sc = fold_sc(stats, g, k);
            float sh = bt[k] - mu * sc;
            s += sh * Wnext[o2 * 64 + k];
        }
        cst[o2] = s;
    } else if (t < 16384 + 512) {
        int i = t - 16384 - 256;
        int k = i >> 2;
        int m = i & 3;
        usc[i] = Unext[m * 64 + k] * fold_sc(stats, g, k);
    }
}

// ---------------------------------------------------------------------------
// Node transform: y2[n][o] = bf16x4 of h@wtT (+cst). Wave per 4 nodes.
// Tail (threads 0..63): p[n][m] = h[n,:]@usc[:,m] for the block's 16 nodes —
// one (node,head) scalar per thread, h rows L1-hot, no extra dispatch.
// (R7 lesson: do NOT compute p wave-uniformly in all 64 lanes.)
// ---------------------------------------------------------------------------
__global__ __launch_bounds__(256) void transform_kernel(const float* __restrict__ h,
                                                        const float4* __restrict__ wt4,
                                                        const float* __restrict__ cst,
                                                        const float* __restrict__ usc,
                                                        ushort4* __restrict__ y2,
                                                        float* __restrict__ pout) {
    int wave = (blockIdx.x * 256 + threadIdx.x) >> 6;  // 0..7499 (exact)
    int lane = threadIdx.x & 63;
    int n0 = wave * 4;
    const float4* h4 = reinterpret_cast<const float4*>(h);

    float acc[4][4];
#pragma unroll
    for (int j = 0; j < 4; ++j)
#pragma unroll
        for (int m = 0; m < 4; ++m) acc[j][m] = 0.0f;

#pragma unroll 4
    for (int kb = 0; kb < 16; ++kb) {
        float hb[4][4];
#pragma unroll
        for (int j = 0; j < 4; ++j) {
            float4 v = h4[(size_t)(n0 + j) * 16 + kb];
            hb[j][0] = v.x; hb[j][1] = v.y; hb[j][2] = v.z; hb[j][3] = v.w;
        }
#pragma unroll
        for (int kk = 0; kk < 4; ++kk) {
            float4 wv = wt4[(size_t)(kb * 4 + kk) * 64 + lane];
#pragma unroll
            for (int j = 0; j < 4; ++j) {
                acc[j][0] += hb[j][kk] * wv.x;
                acc[j][1] += hb[j][kk] * wv.y;
                acc[j][2] += hb[j][kk] * wv.z;
                acc[j][3] += hb[j][kk] * wv.w;
            }
        }
    }
    float c0 = cst[lane];
    float c1 = cst[64 + lane];
    float c2 = cst[128 + lane];
    float c3 = cst[192 + lane];
#pragma unroll
    for (int j = 0; j < 4; ++j) {
        ushort4 o;
        o.x = f2bf(acc[j][0] + c0);
        o.y = f2bf(acc[j][1] + c1);
        o.z = f2bf(acc[j][2] + c2);
        o.w = f2bf(acc[j][3] + c3);
        y2[(size_t)(n0 + j) * 64 + lane] = o;
    }

    // p tail: block covers 16 nodes exactly (1875 * 16 = 30000)
    if (threadIdx.x < 64) {
        int n = blockIdx.x * 16 + (threadIdx.x >> 2);
        int m = threadIdx.x & 3;
        const float4* hn = h4 + (size_t)n * 16;
        float a = 0.0f;
#pragma unroll
        for (int j = 0; j < 16; ++j) {
            float4 hv = hn[j];
            a += hv.x * usc[(4 * j + 0) * 4 + m] + hv.y * usc[(4 * j + 1) * 4 + m] +
                 hv.z * usc[(4 * j + 2) * 4 + m] + hv.w * usc[(4 * j + 3) * 4 + m];
        }
        pout[n * 4 + m] = a;
    }
}

// ---------------------------------------------------------------------------
// Fused aggregate: one wave per dst node, lane = output channel.
// Phase 1 (per 64-edge chunk): each lane computes ONE edge's normalized
// attention (softmax w/ max-sub — REQUIRED, see R5 NaN) into LDS.
// Phase 2: per edge, broadcast attn + src from LDS, gather y2, 4 FMAs.
// 4-wide unroll + 4 accumulators for more outstanding gathers (latency-bound).
// ---------------------------------------------------------------------------
template <int DO_RELU_STATS>
__global__ __launch_bounds__(256) void aggregate_kernel(const int* __restrict__ rowptr,
                                                        const int* __restrict__ csr,
                                                        const float* __restrict__ p,
                                                        const ushort4* __restrict__ y2,
                                                        const float* __restrict__ cvec,
                                                        const float* __restrict__ bvec,
                                                        float* __restrict__ hout,
                                                        float* __restrict__ partial) {
    __shared__ float4 attn_s[4][64];
    __shared__ int src_s[4][64];
    int wid = threadIdx.x >> 6;
    int lane = threadIdx.x & 63;
    int n = blockIdx.x * 4 + wid;
    const float4* p4 = reinterpret_cast<const float4*>(p);

    float4 cv = make_float4(cvec[0], cvec[1], cvec[2], cvec[3]);
    float4 pd = p4[n];
    float4 pdc = make_float4(pd.x + cv.x, pd.y + cv.y, pd.z + cv.z, pd.w + cv.w);

    // self-loop attention = softmax(c), node-independent
    float smx = fmaxf(fmaxf(cv.x, cv.y), fmaxf(cv.z, cv.w));
    float se0 = __expf(cv.x - smx), se1 = __expf(cv.y - smx);
    float se2 = __expf(cv.z - smx), se3 = __expf(cv.w - smx);
    float sinv = 1.0f / (se0 + se1 + se2 + se3);
    ushort4 ws = y2[(unsigned)(n * 64 + lane)];
    float acc0 = (se0 * bf2f(ws.x) + se1 * bf2f(ws.y) +
                  se2 * bf2f(ws.z) + se3 * bf2f(ws.w)) * sinv;
    float acc1 = 0.0f, acc2 = 0.0f, acc3 = 0.0f;

    int start = rowptr[n];
    int end = rowptr[n + 1];
    for (int j = start; j < end; j += 64) {
        int chunk = end - j;
        if (chunk > 64) chunk = 64;
        if (lane < chunk) {
            int s = csr[j + lane];
            float4 q = p4[(unsigned)s];
            float l0 = pdc.x - q.x;
            float l1 = pdc.y - q.y;
            float l2 = pdc.z - q.z;
            float l3 = pdc.w - q.w;
            float mx = fmaxf(fmaxf(l0, l1), fmaxf(l2, l3));
            float e0 = __expf(l0 - mx);
            float e1 = __expf(l1 - mx);
            float e2 = __expf(l2 - mx);
            float e3 = __expf(l3 - mx);
            float inv = 1.0f / (e0 + e1 + e2 + e3);
            attn_s[wid][lane] = make_float4(e0 * inv, e1 * inv, e2 * inv, e3 * inv);
            src_s[wid][lane] = s;
        }
        int k = 0;
        for (; k + 4 <= chunk; k += 4) {
            float4 a0 = attn_s[wid][k];
            int s0 = src_s[wid][k];
            float4 a1 = attn_s[wid][k + 1];
            int s1 = src_s[wid][k + 1];
            float4 a2 = attn_s[wid][k + 2];
            int s2 = src_s[wid][k + 2];
            float4 a3 = attn_s[wid][k + 3];
            int s3 = src_s[wid][k + 3];
            ushort4 w0 = y2[(unsigned)(s0 * 64 + lane)];
            ushort4 w1 = y2[(unsigned)(s1 * 64 + lane)];
            ushort4 w2 = y2[(unsigned)(s2 * 64 + lane)];
            ushort4 w3 = y2[(unsigned)(s3 * 64 + lane)];
            acc0 += a0.x * bf2f(w0.x) + a0.y * bf2f(w0.y) +
                    a0.z * bf2f(w0.z) + a0.w * bf2f(w0.w);
            acc1 += a1.x * bf2f(w1.x) + a1.y * bf2f(w1.y) +
                    a1.z * bf2f(w1.z) + a1.w * bf2f(w1.w);
            acc2 += a2.x * bf2f(w2.x) + a2.y * bf2f(w2.y) +
                    a2.z * bf2f(w2.z) + a2.w * bf2f(w2.w);
            acc3 += a3.x * bf2f(w3.x) + a3.y * bf2f(w3.y) +
                    a3.z * bf2f(w3.z) + a3.w * bf2f(w3.w);
        }
        for (; k < chunk; ++k) {
            float4 a0 = attn_s[wid][k];
            int s0 = src_s[wid][k];
            ushort4 w0 = y2[(unsigned)(s0 * 64 + lane)];
            acc0 += a0.x * bf2f(w0.x) + a0.y * bf2f(w0.y) +
                    a0.z * bf2f(w0.z) + a0.w * bf2f(w0.w);
        }
    }

    float val = ((acc0 + acc1) + (acc2 + acc3)) / (float)(end - start + 1) + bvec[lane];

    if (DO_RELU_STATS) {
        val = fmaxf(val, 0.0f);
        hout[(size_t)n * 64 + lane] = val;
        __shared__ float s1m[256];
        __shared__ float s2m[256];
        s1m[threadIdx.x] = val;
        s2m[threadIdx.x] = val * val;
        __syncthreads();
        if (threadIdx.x < 64) {
            float s = s1m[threadIdx.x] + s1m[threadIdx.x + 64] +
                      s1m[threadIdx.x + 128] + s1m[threadIdx.x + 192];
            float q = s2m[threadIdx.x] + s2m[threadIdx.x + 64] +
                      s2m[threadIdx.x + 128] + s2m[threadIdx.x + 192];
            partial[blockIdx.x * 128 + threadIdx.x] = s;
            partial[blockIdx.x * 128 + 64 + threadIdx.x] = q;
        }
    } else {
        hout[(size_t)n * 64 + lane] = val;
    }
}

// ---------------------------------------------------------------------------
// Reduce per-block partials -> stats[128]. One block per slot.
// ---------------------------------------------------------------------------
__global__ __launch_bounds__(256) void reduce_kernel(const float* __restrict__ partial,
                                                     float* __restrict__ stats) {
    int slot = blockIdx.x;           // 0..127
    float acc = 0.0f;
    for (int j = threadIdx.x; j < NBLK; j += 256)
        acc += partial[(size_t)j * 128 + slot];
    __shared__ float sm[256];
    sm[threadIdx.x] = acc;
    __syncthreads();
    for (int off = 128; off > 0; off >>= 1) {
        if (threadIdx.x < off) sm[threadIdx.x] += sm[threadIdx.x + off];
        __syncthreads();
    }
    if (threadIdx.x == 0) stats[slot] = sm[0];
}

extern "C" void kernel_launch(void* const* d_in, const int* in_sizes, int n_in,
                              void* d_out, int out_size, void* d_ws, size_t ws_size,
                              hipStream_t stream) {
    const float* x = (const float*)d_in[0];
    const void* ei = d_in[1];
    const float* W0 = (const float*)d_in[2];
    const float* U0 = (const float*)d_in[3];
    const float* c0 = (const float*)d_in[4];
    const float* b0 = (const float*)d_in[5];
    const float* g0 = (const float*)d_in[6];
    const float* bt0 = (const float*)d_in[7];
    const float* W1 = (const float*)d_in[8];
    const float* U1 = (const float*)d_in[9];
    const float* c1 = (const float*)d_in[10];
    const float* b1 = (const float*)d_in[11];
    const float* g1 = (const float*)d_in[12];
    const float* bt1 = (const float*)d_in[13];
    const float* W2 = (const float*)d_in[14];
    const float* U2 = (const float*)d_in[15];
    const float* c2 = (const float*)d_in[16];
    const float* b2 = (const float*)d_in[17];

    float* ws = (float*)d_ws;
    float* wt = ws;                          // 3*16384
    float* wsc = wt + 3 * 16384;             // 16384
    float* usc = wsc + 16384;                // 256
    float* cst = usc + 256;                  // 256
    float* u0pack = cst + 256;               // 256
    float* cst0 = u0pack + 256;              // 256
    ushort4* y2 = (ushort4*)(cst0 + 256);    // NN*64 ushort4 (15.36 MB)
    float* p = (float*)((unsigned short*)y2 + (size_t)NN * 256);  // NN*4
    float* h1 = p + (size_t)NN * 4;          // NN*64
    float* h2 = h1 + (size_t)NN * 64;        // NN*64
    float* stats = h2 + (size_t)NN * 64;     // 128
    float* partial = stats + 128;            // NBLK*128
    int* degi = (int*)(partial + (size_t)NBLK * 128);  // NN
    int* cursor = degi + NN;                 // NN  (contiguous w/ degi: 1 memset)
    int* rowptr = cursor + NN;               // NN+1
    int* csr = rowptr + NN + 1;              // NE
    int* bsum = csr + NE;                    // SCB
    int* boff = bsum + SCB;                  // SCB

    const int TB = 256;
    const int tfBlocks = (NN / 4) * 64 / TB;         // 1875 exact
    const int aggBlocks = NBLK;                      // 7500 (wave per node)
    const int eBlocks = NE / TB;                     // 1875 exact
    const int trBlocks = (3 * 16384 + 512 + TB - 1) / TB;  // 194
    const int foldBlocks = (16384 + 512 + TB - 1) / TB;    // 66

    // ---- one-shot prep: weight repack, CSR by dst (detect is inlined) ----
    transpose_kernel<<<trBlocks, TB, 0, stream>>>(W0, W1, W2, U0, wt, u0pack, cst0);
    hipMemsetAsync(degi, 0, sizeof(int) * 2 * NN, stream);
    hist_kernel<<<eBlocks, TB, 0, stream>>>(ei, degi);
    scanA_kernel<<<SCB, TB, 0, stream>>>(degi, bsum);
    scanB_kernel<<<1, 128, 0, stream>>>(bsum, boff);
    scanC_kernel<<<SCB, TB, 0, stream>>>(degi, boff, rowptr);
    scatter_kernel<<<eBlocks, TB, 0, stream>>>(ei, rowptr, cursor, csr);

    const float4* wt4_0 = reinterpret_cast<const float4*>(wt);
    const float4* wsc4 = reinterpret_cast<const float4*>(wsc);

    // ---- layer 0 (no BN in front: raw W0/U0, zero cst) ----
    transform_kernel<<<tfBlocks, TB, 0, stream>>>(x, wt4_0, cst0, u0pack, y2, p);
    aggregate_kernel<1><<<aggBlocks, TB, 0, stream>>>(rowptr, csr, p, y2, c0, b0, h1, partial);
    reduce_kernel<<<128, TB, 0, stream>>>(partial, stats);
    fold_kernel<<<foldBlocks, TB, 0, stream>>>(stats, g0, bt0, W1, U1, wt + 16384, wsc, usc, cst);

    // ---- layer 1 (BN0 folded into W1/U1) ----
    transform_kernel<<<tfBlocks, TB, 0, stream>>>(h1, wsc4, cst, usc, y2, p);
    aggregate_kernel<1><<<aggBlocks, TB, 0, stream>>>(rowptr, csr, p, y2, c1, b1, h2, partial);
    reduce_kernel<<<128, TB, 0, stream>>>(partial, stats);
    fold_kernel<<<foldBlocks, TB, 0, stream>>>(stats, g1, bt1, W2, U2, wt + 2 * 16384, wsc, usc, cst);

    // ---- layer 2 (BN1 folded into W2/U2) ----
    transform_kernel<<<tfBlocks, TB, 0, stream>>>(h2, wsc4, cst, usc, y2, p);
    aggregate_kernel<0><<<aggBlocks, TB, 0, stream>>>(rowptr, csr, p, y2, c2, b2, (float*)d_out, nullptr);
}